// Round 1
// baseline (539.303 us; speedup 1.0000x reference)
//
#include <hip/hip_runtime.h>

#define N_NODES   100000
#define N_EDGES   1600000
#define D         64
#define N_TARGETS 100
#define N_GRAPHS  512

typedef _Float16 half4 __attribute__((ext_vector_type(4)));
typedef _Float16 half8 __attribute__((ext_vector_type(8)));

// ---------------- utility ----------------

__global__ void k_zero_i(int* __restrict__ p, int n) {
    int i = blockIdx.x * blockDim.x + threadIdx.x;
    if (i < n) p[i] = 0;
}

// ---------------- CSR build (simple scatter fill — measured plateau) --------

__global__ void k_deg(const int* __restrict__ dst, int* __restrict__ deg) {
    int e = blockIdx.x * blockDim.x + threadIdx.x;
    if (e < N_EDGES) atomicAdd(&deg[dst[e]], 1);
}

// block-local exclusive scan of deg; also computes dinv (deg already loaded)
__global__ void k_scan1(const int* __restrict__ deg, int* __restrict__ base,
                        int* __restrict__ bsum, float* __restrict__ dinv) {
    __shared__ int s[256];
    int t = threadIdx.x, i = blockIdx.x * 256 + t;
    int v = (i < N_NODES) ? deg[i] : 0;
    if (i < N_NODES) dinv[i] = rsqrtf((float)v + 1.0f);  // +1 self-loop
    s[t] = v;
    __syncthreads();
    for (int off = 1; off < 256; off <<= 1) {
        int x = (t >= off) ? s[t - off] : 0;
        __syncthreads();
        s[t] += x;
        __syncthreads();
    }
    if (i < N_NODES) base[i] = s[t] - v;
    if (t == 255) bsum[blockIdx.x] = s[255];
}

__global__ void k_scan2(int* __restrict__ bsum, int nb) {
    __shared__ int s[512];
    int t = threadIdx.x;
    int v = (t < nb) ? bsum[t] : 0;
    s[t] = v;
    __syncthreads();
    for (int off = 1; off < 512; off <<= 1) {
        int x = (t >= off) ? s[t - off] : 0;
        __syncthreads();
        s[t] += x;
        __syncthreads();
    }
    if (t < nb) bsum[t] = s[t] - v;
}

// add block offsets; zero cursor; set base[N]=E; also zero pooled+counts
__global__ void k_scan3(int* __restrict__ base, const int* __restrict__ bsum,
                        int* __restrict__ cursor, float* __restrict__ poolz) {
    int i = blockIdx.x * blockDim.x + threadIdx.x;
    if (i < N_NODES) {
        base[i] += bsum[i >> 8];
        cursor[i] = 0;
    }
    if (i == 0) base[N_NODES] = N_EDGES;
    if (i < N_GRAPHS * D + N_GRAPHS) poolz[i] = 0.0f;
}

__global__ void k_fill(const int* __restrict__ src, const int* __restrict__ dst,
                       const int* __restrict__ base, int* __restrict__ cursor,
                       int* __restrict__ esrc) {
    int e = blockIdx.x * blockDim.x + threadIdx.x;
    if (e < N_EDGES) {
        int d = dst[e];
        int pos = base[d] + atomicAdd(&cursor[d], 1);
        esrc[pos] = src[e];
    }
}

// ------ matmul (layer 1 only): H16[row] = fp16( X[row] @ W * dinv[row] ) ----
__global__ void __launch_bounds__(256)
k_mm(const float* __restrict__ X, const float* __restrict__ W,
     const float* __restrict__ dinv, _Float16* __restrict__ Y16) {
    __shared__ float Xs[64][68];
    __shared__ float Ws[64][68];
    int tid = threadIdx.x;
    int r0  = blockIdx.x * 64;
    {
        int lr = tid >> 4;
        int lc = (tid & 15) * 4;
#pragma unroll
        for (int i = 0; i < 4; ++i) {
            int row = lr + 16 * i;
            *(float4*)&Ws[row][lc] = *(const float4*)(W + row * 64 + lc);
            int gr = r0 + row;
            if (gr < N_NODES)
                *(float4*)&Xs[row][lc] = *(const float4*)(X + (size_t)gr * 64 + lc);
        }
    }
    __syncthreads();

    int tx = (tid & 15) * 4;
    int ty = (tid >> 4) * 4;
    float acc[4][4] = {{0.f}};

#pragma unroll
    for (int kk = 0; kk < 16; ++kk) {
        float4 a[4], w[4];
#pragma unroll
        for (int r = 0; r < 4; ++r) a[r] = *(float4*)&Xs[ty + r][kk * 4];
#pragma unroll
        for (int k = 0; k < 4; ++k) w[k] = *(float4*)&Ws[kk * 4 + k][tx];
#pragma unroll
        for (int r = 0; r < 4; ++r) {
#pragma unroll
            for (int k = 0; k < 4; ++k) {
                float av = ((const float*)&a[r])[k];
                acc[r][0] = fmaf(av, w[k].x, acc[r][0]);
                acc[r][1] = fmaf(av, w[k].y, acc[r][1]);
                acc[r][2] = fmaf(av, w[k].z, acc[r][2]);
                acc[r][3] = fmaf(av, w[k].w, acc[r][3]);
            }
        }
    }

#pragma unroll
    for (int r = 0; r < 4; ++r) {
        int gr = r0 + ty + r;
        if (gr < N_NODES) {
            float di = dinv[gr];
            half4 o;
            o.x = (_Float16)(acc[r][0] * di);
            o.y = (_Float16)(acc[r][1] * di);
            o.z = (_Float16)(acc[r][2] * di);
            o.w = (_Float16)(acc[r][3] * di);
            *(half4*)(Y16 + (size_t)gr * 64 + tx) = o;
        }
    }
}

// ---- fused pull + next-layer matmul (low-DS epilogue, R11 structure) ----
// Edge loop now has a 16-edge path: deg~Poisson(16) nodes get >=2 gathers
// in flight instead of 1 (latency hiding for the MEDIAN node, not just deg>=32).
__global__ void __launch_bounds__(256)
k_pullmm(const _Float16* __restrict__ H, const int* __restrict__ esrc,
         const int* __restrict__ base, const float* __restrict__ dinv,
         const float* __restrict__ b_in, const float* __restrict__ W,
         _Float16* __restrict__ Hout) {
    __shared__ _Float16 Wh[D * D];   // [k][f] fp16, 8KB
    {
        for (int idx = threadIdx.x; idx < (D * D) / 8; idx += 256) {
            float4 w0 = *(const float4*)(W + idx * 8);
            float4 w1 = *(const float4*)(W + idx * 8 + 4);
            half8 h;
            h[0] = (_Float16)w0.x; h[1] = (_Float16)w0.y;
            h[2] = (_Float16)w0.z; h[3] = (_Float16)w0.w;
            h[4] = (_Float16)w1.x; h[5] = (_Float16)w1.y;
            h[6] = (_Float16)w1.z; h[7] = (_Float16)w1.w;
            *(half8*)&Wh[idx * 8] = h;
        }
    }
    __syncthreads();

    int i    = blockIdx.x * 4 + (threadIdx.x >> 6);
    int lane = threadIdx.x & 63;
    int g = lane >> 3, l = lane & 7;
    int s0 = base[i], s1 = base[i + 1];
    float acc[8] = {0.f, 0.f, 0.f, 0.f, 0.f, 0.f, 0.f, 0.f};
    if (g == 0) {
        half8 sv = *(const half8*)(H + (size_t)i * D + l * 8);
#pragma unroll
        for (int q = 0; q < 8; ++q) acc[q] = (float)sv[q];
    }

    int p = s0;
    while (p < s1) {
        int cnt = s1 - p;
        if (cnt > 64) cnt = 64;
        int ed = (lane < cnt) ? esrc[p + lane] : 0;
        int j = 0;
        for (; j + 32 <= cnt; j += 32) {
            int e0 = __shfl(ed, j + g, 64);
            int e1 = __shfl(ed, j + 8 + g, 64);
            int e2 = __shfl(ed, j + 16 + g, 64);
            int e3 = __shfl(ed, j + 24 + g, 64);
            half8 v0 = *(const half8*)(H + (size_t)e0 * D + l * 8);
            half8 v1 = *(const half8*)(H + (size_t)e1 * D + l * 8);
            half8 v2 = *(const half8*)(H + (size_t)e2 * D + l * 8);
            half8 v3 = *(const half8*)(H + (size_t)e3 * D + l * 8);
#pragma unroll
            for (int q = 0; q < 8; ++q)
                acc[q] += ((float)v0[q] + (float)v1[q]) + ((float)v2[q] + (float)v3[q]);
        }
        for (; j + 16 <= cnt; j += 16) {
            int e0 = __shfl(ed, j + g, 64);
            int e1 = __shfl(ed, j + 8 + g, 64);
            half8 v0 = *(const half8*)(H + (size_t)e0 * D + l * 8);
            half8 v1 = *(const half8*)(H + (size_t)e1 * D + l * 8);
#pragma unroll
            for (int q = 0; q < 8; ++q)
                acc[q] += (float)v0[q] + (float)v1[q];
        }
        for (; j + 8 <= cnt; j += 8) {
            int e0 = __shfl(ed, j + g, 64);
            half8 v0 = *(const half8*)(H + (size_t)e0 * D + l * 8);
#pragma unroll
            for (int q = 0; q < 8; ++q) acc[q] += (float)v0[q];
        }
        if (j < cnt) {
            int idx = j + g;
            int e0 = __shfl(ed, idx & 63, 64);
            if (idx < cnt) {
                half8 v0 = *(const half8*)(H + (size_t)e0 * D + l * 8);
#pragma unroll
                for (int q = 0; q < 8; ++q) acc[q] += (float)v0[q];
            }
        }
        p += cnt;
    }
#pragma unroll
    for (int off = 8; off <= 32; off <<= 1) {
#pragma unroll
        for (int q = 0; q < 8; ++q)
            acc[q] += __shfl_xor(acc[q], off, 64);
    }

    float di = dinv[i];
    float a[8];
    {
        float4 bl0 = *(const float4*)(b_in + l * 8);
        float4 bl1 = *(const float4*)(b_in + l * 8 + 4);
        a[0] = fmaxf(fmaf(acc[0], di, bl0.x), 0.f);
        a[1] = fmaxf(fmaf(acc[1], di, bl0.y), 0.f);
        a[2] = fmaxf(fmaf(acc[2], di, bl0.z), 0.f);
        a[3] = fmaxf(fmaf(acc[3], di, bl0.w), 0.f);
        a[4] = fmaxf(fmaf(acc[4], di, bl1.x), 0.f);
        a[5] = fmaxf(fmaf(acc[5], di, bl1.y), 0.f);
        a[6] = fmaxf(fmaf(acc[6], di, bl1.z), 0.f);
        a[7] = fmaxf(fmaf(acc[7], di, bl1.w), 0.f);
    }

    float part[8] = {0.f, 0.f, 0.f, 0.f, 0.f, 0.f, 0.f, 0.f};
#pragma unroll
    for (int q = 0; q < 8; ++q) {
        half8 wv = *(const half8*)&Wh[(l * 8 + q) * D + g * 8];
        float aq = a[q];
#pragma unroll
        for (int m = 0; m < 8; ++m)
            part[m] = fmaf(aq, (float)wv[m], part[m]);
    }
#pragma unroll
    for (int off = 1; off <= 4; off <<= 1) {
#pragma unroll
        for (int m = 0; m < 8; ++m)
            part[m] += __shfl_xor(part[m], off, 64);
    }
    if (l == 0) {
        half8 o;
#pragma unroll
        for (int m = 0; m < 8; ++m) o[m] = (_Float16)(part[m] * di);
        *(half8*)(Hout + (size_t)i * D + g * 8) = o;
    }
}

// ---------------- final pull (layer 3): fp16 AGG out for pooling ----------
__global__ void __launch_bounds__(256)
k_pull(const _Float16* __restrict__ H, const int* __restrict__ esrc,
       const int* __restrict__ base, const float* __restrict__ dinv,
       const float* __restrict__ b, _Float16* __restrict__ AGG16) {
    int i    = blockIdx.x * 4 + (threadIdx.x >> 6);
    int lane = threadIdx.x & 63;
    int g = lane >> 3, l = lane & 7;
    int s0 = base[i], s1 = base[i + 1];
    float acc[8] = {0.f, 0.f, 0.f, 0.f, 0.f, 0.f, 0.f, 0.f};
    if (g == 0) {
        half8 sv = *(const half8*)(H + (size_t)i * D + l * 8);
#pragma unroll
        for (int q = 0; q < 8; ++q) acc[q] = (float)sv[q];
    }

    int p = s0;
    while (p < s1) {
        int cnt = s1 - p;
        if (cnt > 64) cnt = 64;
        int ed = (lane < cnt) ? esrc[p + lane] : 0;
        int j = 0;
        for (; j + 32 <= cnt; j += 32) {
            int e0 = __shfl(ed, j + g, 64);
            int e1 = __shfl(ed, j + 8 + g, 64);
            int e2 = __shfl(ed, j + 16 + g, 64);
            int e3 = __shfl(ed, j + 24 + g, 64);
            half8 v0 = *(const half8*)(H + (size_t)e0 * D + l * 8);
            half8 v1 = *(const half8*)(H + (size_t)e1 * D + l * 8);
            half8 v2 = *(const half8*)(H + (size_t)e2 * D + l * 8);
            half8 v3 = *(const half8*)(H + (size_t)e3 * D + l * 8);
#pragma unroll
            for (int q = 0; q < 8; ++q)
                acc[q] += ((float)v0[q] + (float)v1[q]) + ((float)v2[q] + (float)v3[q]);
        }
        for (; j + 16 <= cnt; j += 16) {
            int e0 = __shfl(ed, j + g, 64);
            int e1 = __shfl(ed, j + 8 + g, 64);
            half8 v0 = *(const half8*)(H + (size_t)e0 * D + l * 8);
            half8 v1 = *(const half8*)(H + (size_t)e1 * D + l * 8);
#pragma unroll
            for (int q = 0; q < 8; ++q)
                acc[q] += (float)v0[q] + (float)v1[q];
        }
        for (; j + 8 <= cnt; j += 8) {
            int e0 = __shfl(ed, j + g, 64);
            half8 v0 = *(const half8*)(H + (size_t)e0 * D + l * 8);
#pragma unroll
            for (int q = 0; q < 8; ++q) acc[q] += (float)v0[q];
        }
        if (j < cnt) {
            int idx = j + g;
            int e0 = __shfl(ed, idx & 63, 64);
            if (idx < cnt) {
                half8 v0 = *(const half8*)(H + (size_t)e0 * D + l * 8);
#pragma unroll
                for (int q = 0; q < 8; ++q) acc[q] += (float)v0[q];
            }
        }
        p += cnt;
    }
#pragma unroll
    for (int off = 8; off <= 32; off <<= 1) {
#pragma unroll
        for (int q = 0; q < 8; ++q)
            acc[q] += __shfl_xor(acc[q], off, 64);
    }

    if (g == 0) {
        float di = dinv[i];
        float4 bl0 = *(const float4*)(b + l * 8);
        float4 bl1 = *(const float4*)(b + l * 8 + 4);
        half8 o;
        o[0] = (_Float16)fmaf(acc[0], di, bl0.x);
        o[1] = (_Float16)fmaf(acc[1], di, bl0.y);
        o[2] = (_Float16)fmaf(acc[2], di, bl0.z);
        o[3] = (_Float16)fmaf(acc[3], di, bl0.w);
        o[4] = (_Float16)fmaf(acc[4], di, bl1.x);
        o[5] = (_Float16)fmaf(acc[5], di, bl1.y);
        o[6] = (_Float16)fmaf(acc[6], di, bl1.z);
        o[7] = (_Float16)fmaf(acc[7], di, bl1.w);
        *(half8*)(AGG16 + (size_t)i * D + l * 8) = o;
    }
}

// ---- segment-sorted pooling (fp16 in, fp32 accumulate, fused counts) ----
__global__ void __launch_bounds__(256)
k_pool_seg(const _Float16* __restrict__ H16, const int* __restrict__ seg,
           float* __restrict__ pooled, float* __restrict__ counts) {
    int wave = threadIdx.x >> 6;
    int lane = threadIdx.x & 63;
    int n0 = (blockIdx.x * 4 + wave) * 64;
    if (n0 >= N_NODES) return;
    int nEnd = n0 + 64;
    if (nEnd > N_NODES) nEnd = N_NODES;
    int cur = seg[n0];
    float acc = 0.0f;
    int run = 0;
    for (int n = n0; n < nEnd; ++n) {
        int gsg = seg[n];  // wave-uniform
        if (gsg != cur) {
            atomicAdd(&pooled[(size_t)cur * D + lane], acc);
            if (lane == 0) atomicAdd(&counts[cur], (float)run);
            acc = 0.0f; run = 0;
            cur = gsg;
        }
        acc += (float)H16[(size_t)n * D + lane];
        run += 1;
    }
    atomicAdd(&pooled[(size_t)cur * D + lane], acc);
    if (lane == 0) atomicAdd(&counts[cur], (float)run);
}

// ---------------- head ----------------
__global__ void k_out(const float* __restrict__ pooled, const float* __restrict__ counts,
                      const float* __restrict__ Wout, const float* __restrict__ bout,
                      float* __restrict__ out) {
    __shared__ float prow[D];
    int g = blockIdx.x;
    int t = threadIdx.x;
    if (t < D) prow[t] = pooled[(size_t)g * D + t] / fmaxf(counts[g], 1.0f);
    __syncthreads();
    if (t < N_TARGETS) {
        float acc = bout[t];
#pragma unroll
        for (int k = 0; k < D; ++k)
            acc = fmaf(prow[k], Wout[k * N_TARGETS + t], acc);
        out[g * N_TARGETS + t] = acc;
    }
}

// ---------------- driver ----------------

extern "C" void kernel_launch(void* const* d_in, const int* in_sizes, int n_in,
                              void* d_out, int out_size, void* d_ws, size_t ws_size,
                              hipStream_t stream) {
    const float* x    = (const float*)d_in[0];
    const float* W1   = (const float*)d_in[1];
    const float* b1   = (const float*)d_in[2];
    const float* W2   = (const float*)d_in[3];
    const float* b2   = (const float*)d_in[4];
    const float* W3   = (const float*)d_in[5];
    const float* b3   = (const float*)d_in[6];
    const float* Wout = (const float*)d_in[7];
    const float* bout = (const float*)d_in[8];
    const int*   eidx = (const int*)d_in[9];
    const int*   seg  = (const int*)d_in[10];
    const int* src = eidx;
    const int* dst = eidx + N_EDGES;
    float* out = (float*)d_out;

    // workspace layout (~34 MB). AGG16 aliases H16B (dead after pullmm#2).
    _Float16* H16A   = (_Float16*)d_ws;                       // 6.4M halfs
    _Float16* H16B   = H16A + (size_t)N_NODES * D;            // 6.4M halfs
    _Float16* AGG16  = H16B;                                  // alias
    int*      esrc   = (int*)(H16B + (size_t)N_NODES * D);    // 1.6M
    float*    dinv   = (float*)(esrc + N_EDGES);              // 100k
    int*      degc   = (int*)(dinv + N_NODES);                // 100k (deg, then cursor)
    int*      base   = degc + N_NODES;                        // 100k+1 (+pad)
    int*      bsum   = base + N_NODES + 4;                    // 512
    float*    pooled = (float*)(bsum + 512);                  // 32768
    float*    counts = pooled + N_GRAPHS * D;                 // 512 (contiguous)

    const int NB = (N_NODES + 255) / 256;  // 391

    // ---- CSR build ----
    k_zero_i<<<NB, 256, 0, stream>>>(degc, N_NODES);
    k_deg<<<N_EDGES / 256, 256, 0, stream>>>(dst, degc);
    k_scan1<<<NB, 256, 0, stream>>>(degc, base, bsum, dinv);
    k_scan2<<<1, 512, 0, stream>>>(bsum, NB);
    k_scan3<<<NB, 256, 0, stream>>>(base, bsum, degc, pooled);  // zeroes pooled+counts too
    k_fill<<<N_EDGES / 256, 256, 0, stream>>>(src, dst, base, degc, esrc);

    // ---- 3 GCN layers (mm1 separate; mm2/mm3 fused into pulls) ----
    const int MMB = (N_NODES + 63) / 64;  // 1563
    k_mm<<<MMB, 256, 0, stream>>>(x, W1, dinv, H16A);
    k_pullmm<<<N_NODES / 4, 256, 0, stream>>>(H16A, esrc, base, dinv, b1, W2, H16B);
    k_pullmm<<<N_NODES / 4, 256, 0, stream>>>(H16B, esrc, base, dinv, b2, W3, H16A);
    k_pull<<<N_NODES / 4, 256, 0, stream>>>(H16A, esrc, base, dinv, b3, AGG16);

    // ---- mean pool (sorted-segment, fused counts) + head ----
    k_pool_seg<<<NB, 256, 0, stream>>>(AGG16, seg, pooled, counts);
    k_out<<<N_GRAPHS, 128, 0, stream>>>(pooled, counts, Wout, bout, out);
}

// Round 2
// 491.779 us; speedup vs baseline: 1.0966x; 1.0966x over previous
//
#include <hip/hip_runtime.h>

#define N_NODES   100000
#define N_EDGES   1600000
#define D         64
#define N_TARGETS 100
#define N_GRAPHS  512
#define NBUCK     391     // ceil(N_NODES / 256): bucket b = dst >> 8
#define EPB       4096    // edges per block in pass A

typedef _Float16 half4 __attribute__((ext_vector_type(4)));
typedef _Float16 half8 __attribute__((ext_vector_type(8)));

// ---------------- utility ----------------

__global__ void k_zero_i(int* __restrict__ p, int n) {
    int i = blockIdx.x * blockDim.x + threadIdx.x;
    if (i < n) p[i] = 0;
}

// ---------------- CSR build ----------------

__global__ void k_deg(const int* __restrict__ dst, int* __restrict__ deg) {
    int e = blockIdx.x * blockDim.x + threadIdx.x;
    if (e < N_EDGES) atomicAdd(&deg[dst[e]], 1);
}

// block-local exclusive scan of deg; also computes dinv (deg already loaded)
__global__ void k_scan1(const int* __restrict__ deg, int* __restrict__ base,
                        int* __restrict__ bsum, float* __restrict__ dinv) {
    __shared__ int s[256];
    int t = threadIdx.x, i = blockIdx.x * 256 + t;
    int v = (i < N_NODES) ? deg[i] : 0;
    if (i < N_NODES) dinv[i] = rsqrtf((float)v + 1.0f);  // +1 self-loop
    s[t] = v;
    __syncthreads();
    for (int off = 1; off < 256; off <<= 1) {
        int x = (t >= off) ? s[t - off] : 0;
        __syncthreads();
        s[t] += x;
        __syncthreads();
    }
    if (i < N_NODES) base[i] = s[t] - v;
    if (t == 255) bsum[blockIdx.x] = s[255];
}

__global__ void k_scan2(int* __restrict__ bsum, int nb) {
    __shared__ int s[512];
    int t = threadIdx.x;
    int v = (t < nb) ? bsum[t] : 0;
    s[t] = v;
    __syncthreads();
    for (int off = 1; off < 512; off <<= 1) {
        int x = (t >= off) ? s[t - off] : 0;
        __syncthreads();
        s[t] += x;
        __syncthreads();
    }
    if (t < nb) bsum[t] = s[t] - v;
}

// add block offsets; zero cursor + bucket cursor; set base[N]=E; zero pooled+counts
__global__ void k_scan3(int* __restrict__ base, const int* __restrict__ bsum,
                        int* __restrict__ cursor, int* __restrict__ gcur,
                        float* __restrict__ poolz) {
    int i = blockIdx.x * blockDim.x + threadIdx.x;
    if (i < N_NODES) {
        base[i] += bsum[i >> 8];
        cursor[i] = 0;
    }
    if (i == 0) base[N_NODES] = N_EDGES;
    if (i < NBUCK) gcur[i] = 0;
    if (i < N_GRAPHS * D + N_GRAPHS) poolz[i] = 0.0f;
}

// ---- pass A: bucket edges by dst>>8 into staging at final-CSR bucket offsets ----
// LDS histogram gives per-edge rank; one global atomic per (block,bucket) reserves
// a dense slice. Staged writes fill cache lines densely (vs 17x write-amp scatter).
__global__ void __launch_bounds__(256)
k_binA(const int* __restrict__ src, const int* __restrict__ dst,
       const int* __restrict__ base, int* __restrict__ gcur,
       unsigned long long* __restrict__ staged) {
    __shared__ int hist[NBUCK];
    __shared__ int boff[NBUCK];   // final staging offset for this block's slice
    int tid = threadIdx.x;
    for (int i = tid; i < NBUCK; i += 256) hist[i] = 0;
    __syncthreads();

    int e0 = blockIdx.x * EPB;
    int s_[16], d_[16], r_[16];
#pragma unroll
    for (int k = 0; k < 16; ++k) {
        int e = e0 + k * 256 + tid;
        if (e < N_EDGES) {
            s_[k] = src[e];
            d_[k] = dst[e];
            r_[k] = atomicAdd(&hist[d_[k] >> 8], 1);
        } else {
            d_[k] = -1;
        }
    }
    __syncthreads();
    for (int b = tid; b < NBUCK; b += 256) {
        int h = hist[b];
        int base_b = base[b << 8];  // bucket start in edge space (b<<8 <= N_NODES here only if valid; NBUCK-1 start < N)
        boff[b] = base_b + (h > 0 ? atomicAdd(&gcur[b], h) : 0);
    }
    __syncthreads();
#pragma unroll
    for (int k = 0; k < 16; ++k) {
        if (d_[k] >= 0) {
            int b = d_[k] >> 8;
            staged[boff[b] + r_[k]] =
                ((unsigned long long)(unsigned)d_[k] << 32) | (unsigned)s_[k];
        }
    }
}

// ---- pass B: one block per bucket; resolve exact CSR slots (node-local atomics,
// 1KB cursor window / ~16KB esrc window per block → fully L2-local) ----
__global__ void __launch_bounds__(256)
k_binB(const unsigned long long* __restrict__ staged, const int* __restrict__ base,
       int* __restrict__ cursor, int* __restrict__ esrc) {
    int b  = blockIdx.x;
    int n1 = (b << 8) + 256; if (n1 > N_NODES) n1 = N_NODES;
    int s0 = base[b << 8];
    int s1 = base[n1];
    for (int k = s0 + threadIdx.x; k < s1; k += 256) {
        unsigned long long pd = staged[k];
        int d = (int)(pd >> 32);
        int s = (int)(pd & 0xffffffffu);
        int pos = base[d] + atomicAdd(&cursor[d], 1);
        esrc[pos] = s;
    }
}

// ------ matmul (layer 1 only): H16[row] = fp16( X[row] @ W * dinv[row] ) ----
__global__ void __launch_bounds__(256)
k_mm(const float* __restrict__ X, const float* __restrict__ W,
     const float* __restrict__ dinv, _Float16* __restrict__ Y16) {
    __shared__ float Xs[64][68];
    __shared__ float Ws[64][68];
    int tid = threadIdx.x;
    int r0  = blockIdx.x * 64;
    {
        int lr = tid >> 4;
        int lc = (tid & 15) * 4;
#pragma unroll
        for (int i = 0; i < 4; ++i) {
            int row = lr + 16 * i;
            *(float4*)&Ws[row][lc] = *(const float4*)(W + row * 64 + lc);
            int gr = r0 + row;
            if (gr < N_NODES)
                *(float4*)&Xs[row][lc] = *(const float4*)(X + (size_t)gr * 64 + lc);
        }
    }
    __syncthreads();

    int tx = (tid & 15) * 4;
    int ty = (tid >> 4) * 4;
    float acc[4][4] = {{0.f}};

#pragma unroll
    for (int kk = 0; kk < 16; ++kk) {
        float4 a[4], w[4];
#pragma unroll
        for (int r = 0; r < 4; ++r) a[r] = *(float4*)&Xs[ty + r][kk * 4];
#pragma unroll
        for (int k = 0; k < 4; ++k) w[k] = *(float4*)&Ws[kk * 4 + k][tx];
#pragma unroll
        for (int r = 0; r < 4; ++r) {
#pragma unroll
            for (int k = 0; k < 4; ++k) {
                float av = ((const float*)&a[r])[k];
                acc[r][0] = fmaf(av, w[k].x, acc[r][0]);
                acc[r][1] = fmaf(av, w[k].y, acc[r][1]);
                acc[r][2] = fmaf(av, w[k].z, acc[r][2]);
                acc[r][3] = fmaf(av, w[k].w, acc[r][3]);
            }
        }
    }

#pragma unroll
    for (int r = 0; r < 4; ++r) {
        int gr = r0 + ty + r;
        if (gr < N_NODES) {
            float di = dinv[gr];
            half4 o;
            o.x = (_Float16)(acc[r][0] * di);
            o.y = (_Float16)(acc[r][1] * di);
            o.z = (_Float16)(acc[r][2] * di);
            o.w = (_Float16)(acc[r][3] * di);
            *(half4*)(Y16 + (size_t)gr * 64 + tx) = o;
        }
    }
}

// ---- fused pull + next-layer matmul (low-DS epilogue, R11 structure) ----
__global__ void __launch_bounds__(256)
k_pullmm(const _Float16* __restrict__ H, const int* __restrict__ esrc,
         const int* __restrict__ base, const float* __restrict__ dinv,
         const float* __restrict__ b_in, const float* __restrict__ W,
         _Float16* __restrict__ Hout) {
    __shared__ _Float16 Wh[D * D];   // [k][f] fp16, 8KB
    {
        for (int idx = threadIdx.x; idx < (D * D) / 8; idx += 256) {
            float4 w0 = *(const float4*)(W + idx * 8);
            float4 w1 = *(const float4*)(W + idx * 8 + 4);
            half8 h;
            h[0] = (_Float16)w0.x; h[1] = (_Float16)w0.y;
            h[2] = (_Float16)w0.z; h[3] = (_Float16)w0.w;
            h[4] = (_Float16)w1.x; h[5] = (_Float16)w1.y;
            h[6] = (_Float16)w1.z; h[7] = (_Float16)w1.w;
            *(half8*)&Wh[idx * 8] = h;
        }
    }
    __syncthreads();

    int i    = blockIdx.x * 4 + (threadIdx.x >> 6);
    int lane = threadIdx.x & 63;
    int g = lane >> 3, l = lane & 7;
    int s0 = base[i], s1 = base[i + 1];
    float acc[8] = {0.f, 0.f, 0.f, 0.f, 0.f, 0.f, 0.f, 0.f};
    if (g == 0) {
        half8 sv = *(const half8*)(H + (size_t)i * D + l * 8);
#pragma unroll
        for (int q = 0; q < 8; ++q) acc[q] = (float)sv[q];
    }

    int p = s0;
    while (p < s1) {
        int cnt = s1 - p;
        if (cnt > 64) cnt = 64;
        int ed = (lane < cnt) ? esrc[p + lane] : 0;
        int j = 0;
        for (; j + 32 <= cnt; j += 32) {
            int e0 = __shfl(ed, j + g, 64);
            int e1 = __shfl(ed, j + 8 + g, 64);
            int e2 = __shfl(ed, j + 16 + g, 64);
            int e3 = __shfl(ed, j + 24 + g, 64);
            half8 v0 = *(const half8*)(H + (size_t)e0 * D + l * 8);
            half8 v1 = *(const half8*)(H + (size_t)e1 * D + l * 8);
            half8 v2 = *(const half8*)(H + (size_t)e2 * D + l * 8);
            half8 v3 = *(const half8*)(H + (size_t)e3 * D + l * 8);
#pragma unroll
            for (int q = 0; q < 8; ++q)
                acc[q] += ((float)v0[q] + (float)v1[q]) + ((float)v2[q] + (float)v3[q]);
        }
        for (; j + 16 <= cnt; j += 16) {
            int e0 = __shfl(ed, j + g, 64);
            int e1 = __shfl(ed, j + 8 + g, 64);
            half8 v0 = *(const half8*)(H + (size_t)e0 * D + l * 8);
            half8 v1 = *(const half8*)(H + (size_t)e1 * D + l * 8);
#pragma unroll
            for (int q = 0; q < 8; ++q)
                acc[q] += (float)v0[q] + (float)v1[q];
        }
        for (; j + 8 <= cnt; j += 8) {
            int e0 = __shfl(ed, j + g, 64);
            half8 v0 = *(const half8*)(H + (size_t)e0 * D + l * 8);
#pragma unroll
            for (int q = 0; q < 8; ++q) acc[q] += (float)v0[q];
        }
        if (j < cnt) {
            int idx = j + g;
            int e0 = __shfl(ed, idx & 63, 64);
            if (idx < cnt) {
                half8 v0 = *(const half8*)(H + (size_t)e0 * D + l * 8);
#pragma unroll
                for (int q = 0; q < 8; ++q) acc[q] += (float)v0[q];
            }
        }
        p += cnt;
    }
#pragma unroll
    for (int off = 8; off <= 32; off <<= 1) {
#pragma unroll
        for (int q = 0; q < 8; ++q)
            acc[q] += __shfl_xor(acc[q], off, 64);
    }

    float di = dinv[i];
    float a[8];
    {
        float4 bl0 = *(const float4*)(b_in + l * 8);
        float4 bl1 = *(const float4*)(b_in + l * 8 + 4);
        a[0] = fmaxf(fmaf(acc[0], di, bl0.x), 0.f);
        a[1] = fmaxf(fmaf(acc[1], di, bl0.y), 0.f);
        a[2] = fmaxf(fmaf(acc[2], di, bl0.z), 0.f);
        a[3] = fmaxf(fmaf(acc[3], di, bl0.w), 0.f);
        a[4] = fmaxf(fmaf(acc[4], di, bl1.x), 0.f);
        a[5] = fmaxf(fmaf(acc[5], di, bl1.y), 0.f);
        a[6] = fmaxf(fmaf(acc[6], di, bl1.z), 0.f);
        a[7] = fmaxf(fmaf(acc[7], di, bl1.w), 0.f);
    }

    float part[8] = {0.f, 0.f, 0.f, 0.f, 0.f, 0.f, 0.f, 0.f};
#pragma unroll
    for (int q = 0; q < 8; ++q) {
        half8 wv = *(const half8*)&Wh[(l * 8 + q) * D + g * 8];
        float aq = a[q];
#pragma unroll
        for (int m = 0; m < 8; ++m)
            part[m] = fmaf(aq, (float)wv[m], part[m]);
    }
#pragma unroll
    for (int off = 1; off <= 4; off <<= 1) {
#pragma unroll
        for (int m = 0; m < 8; ++m)
            part[m] += __shfl_xor(part[m], off, 64);
    }
    if (l == 0) {
        half8 o;
#pragma unroll
        for (int m = 0; m < 8; ++m) o[m] = (_Float16)(part[m] * di);
        *(half8*)(Hout + (size_t)i * D + g * 8) = o;
    }
}

// ---------------- final pull (layer 3): fp16 AGG out for pooling ----------
__global__ void __launch_bounds__(256)
k_pull(const _Float16* __restrict__ H, const int* __restrict__ esrc,
       const int* __restrict__ base, const float* __restrict__ dinv,
       const float* __restrict__ b, _Float16* __restrict__ AGG16) {
    int i    = blockIdx.x * 4 + (threadIdx.x >> 6);
    int lane = threadIdx.x & 63;
    int g = lane >> 3, l = lane & 7;
    int s0 = base[i], s1 = base[i + 1];
    float acc[8] = {0.f, 0.f, 0.f, 0.f, 0.f, 0.f, 0.f, 0.f};
    if (g == 0) {
        half8 sv = *(const half8*)(H + (size_t)i * D + l * 8);
#pragma unroll
        for (int q = 0; q < 8; ++q) acc[q] = (float)sv[q];
    }

    int p = s0;
    while (p < s1) {
        int cnt = s1 - p;
        if (cnt > 64) cnt = 64;
        int ed = (lane < cnt) ? esrc[p + lane] : 0;
        int j = 0;
        for (; j + 32 <= cnt; j += 32) {
            int e0 = __shfl(ed, j + g, 64);
            int e1 = __shfl(ed, j + 8 + g, 64);
            int e2 = __shfl(ed, j + 16 + g, 64);
            int e3 = __shfl(ed, j + 24 + g, 64);
            half8 v0 = *(const half8*)(H + (size_t)e0 * D + l * 8);
            half8 v1 = *(const half8*)(H + (size_t)e1 * D + l * 8);
            half8 v2 = *(const half8*)(H + (size_t)e2 * D + l * 8);
            half8 v3 = *(const half8*)(H + (size_t)e3 * D + l * 8);
#pragma unroll
            for (int q = 0; q < 8; ++q)
                acc[q] += ((float)v0[q] + (float)v1[q]) + ((float)v2[q] + (float)v3[q]);
        }
        for (; j + 16 <= cnt; j += 16) {
            int e0 = __shfl(ed, j + g, 64);
            int e1 = __shfl(ed, j + 8 + g, 64);
            half8 v0 = *(const half8*)(H + (size_t)e0 * D + l * 8);
            half8 v1 = *(const half8*)(H + (size_t)e1 * D + l * 8);
#pragma unroll
            for (int q = 0; q < 8; ++q)
                acc[q] += (float)v0[q] + (float)v1[q];
        }
        for (; j + 8 <= cnt; j += 8) {
            int e0 = __shfl(ed, j + g, 64);
            half8 v0 = *(const half8*)(H + (size_t)e0 * D + l * 8);
#pragma unroll
            for (int q = 0; q < 8; ++q) acc[q] += (float)v0[q];
        }
        if (j < cnt) {
            int idx = j + g;
            int e0 = __shfl(ed, idx & 63, 64);
            if (idx < cnt) {
                half8 v0 = *(const half8*)(H + (size_t)e0 * D + l * 8);
#pragma unroll
                for (int q = 0; q < 8; ++q) acc[q] += (float)v0[q];
            }
        }
        p += cnt;
    }
#pragma unroll
    for (int off = 8; off <= 32; off <<= 1) {
#pragma unroll
        for (int q = 0; q < 8; ++q)
            acc[q] += __shfl_xor(acc[q], off, 64);
    }

    if (g == 0) {
        float di = dinv[i];
        float4 bl0 = *(const float4*)(b + l * 8);
        float4 bl1 = *(const float4*)(b + l * 8 + 4);
        half8 o;
        o[0] = (_Float16)fmaf(acc[0], di, bl0.x);
        o[1] = (_Float16)fmaf(acc[1], di, bl0.y);
        o[2] = (_Float16)fmaf(acc[2], di, bl0.z);
        o[3] = (_Float16)fmaf(acc[3], di, bl0.w);
        o[4] = (_Float16)fmaf(acc[4], di, bl1.x);
        o[5] = (_Float16)fmaf(acc[5], di, bl1.y);
        o[6] = (_Float16)fmaf(acc[6], di, bl1.z);
        o[7] = (_Float16)fmaf(acc[7], di, bl1.w);
        *(half8*)(AGG16 + (size_t)i * D + l * 8) = o;
    }
}

// ---- segment-sorted pooling (fp16 in, fp32 accumulate, fused counts) ----
__global__ void __launch_bounds__(256)
k_pool_seg(const _Float16* __restrict__ H16, const int* __restrict__ seg,
           float* __restrict__ pooled, float* __restrict__ counts) {
    int wave = threadIdx.x >> 6;
    int lane = threadIdx.x & 63;
    int n0 = (blockIdx.x * 4 + wave) * 64;
    if (n0 >= N_NODES) return;
    int nEnd = n0 + 64;
    if (nEnd > N_NODES) nEnd = N_NODES;
    int cur = seg[n0];
    float acc = 0.0f;
    int run = 0;
    for (int n = n0; n < nEnd; ++n) {
        int gsg = seg[n];  // wave-uniform
        if (gsg != cur) {
            atomicAdd(&pooled[(size_t)cur * D + lane], acc);
            if (lane == 0) atomicAdd(&counts[cur], (float)run);
            acc = 0.0f; run = 0;
            cur = gsg;
        }
        acc += (float)H16[(size_t)n * D + lane];
        run += 1;
    }
    atomicAdd(&pooled[(size_t)cur * D + lane], acc);
    if (lane == 0) atomicAdd(&counts[cur], (float)run);
}

// ---------------- head ----------------
__global__ void k_out(const float* __restrict__ pooled, const float* __restrict__ counts,
                      const float* __restrict__ Wout, const float* __restrict__ bout,
                      float* __restrict__ out) {
    __shared__ float prow[D];
    int g = blockIdx.x;
    int t = threadIdx.x;
    if (t < D) prow[t] = pooled[(size_t)g * D + t] / fmaxf(counts[g], 1.0f);
    __syncthreads();
    if (t < N_TARGETS) {
        float acc = bout[t];
#pragma unroll
        for (int k = 0; k < D; ++k)
            acc = fmaf(prow[k], Wout[k * N_TARGETS + t], acc);
        out[g * N_TARGETS + t] = acc;
    }
}

// ---------------- driver ----------------

extern "C" void kernel_launch(void* const* d_in, const int* in_sizes, int n_in,
                              void* d_out, int out_size, void* d_ws, size_t ws_size,
                              hipStream_t stream) {
    const float* x    = (const float*)d_in[0];
    const float* W1   = (const float*)d_in[1];
    const float* b1   = (const float*)d_in[2];
    const float* W2   = (const float*)d_in[3];
    const float* b2   = (const float*)d_in[4];
    const float* W3   = (const float*)d_in[5];
    const float* b3   = (const float*)d_in[6];
    const float* Wout = (const float*)d_in[7];
    const float* bout = (const float*)d_in[8];
    const int*   eidx = (const int*)d_in[9];
    const int*   seg  = (const int*)d_in[10];
    const int* src = eidx;
    const int* dst = eidx + N_EDGES;
    float* out = (float*)d_out;

    // workspace layout (~34 MB). AGG16 aliases H16B; binA staging aliases H16A
    // (both dead/not-yet-live during CSR build, stream-ordered).
    _Float16* H16A   = (_Float16*)d_ws;                       // 6.4M halfs (12.8MB)
    _Float16* H16B   = H16A + (size_t)N_NODES * D;            // 6.4M halfs
    _Float16* AGG16  = H16B;                                  // alias
    unsigned long long* staged = (unsigned long long*)H16A;   // alias: 1.6M pairs
    int*      esrc   = (int*)(H16B + (size_t)N_NODES * D);    // 1.6M
    float*    dinv   = (float*)(esrc + N_EDGES);              // 100k
    int*      degc   = (int*)(dinv + N_NODES);                // 100k (deg, then cursor)
    int*      base   = degc + N_NODES;                        // 100k+1 (+pad)
    int*      bsum   = base + N_NODES + 4;                    // 512
    float*    pooled = (float*)(bsum + 512);                  // 32768
    float*    counts = pooled + N_GRAPHS * D;                 // 512
    int*      gcur   = (int*)(counts + N_GRAPHS);             // 391 bucket cursors

    const int NB = (N_NODES + 255) / 256;  // 391

    // ---- CSR build (two-pass bucketed scatter) ----
    k_zero_i<<<NB, 256, 0, stream>>>(degc, N_NODES);
    k_deg<<<N_EDGES / 256, 256, 0, stream>>>(dst, degc);
    k_scan1<<<NB, 256, 0, stream>>>(degc, base, bsum, dinv);
    k_scan2<<<1, 512, 0, stream>>>(bsum, NB);
    k_scan3<<<NB, 256, 0, stream>>>(base, bsum, degc, gcur, pooled);
    k_binA<<<(N_EDGES + EPB - 1) / EPB, 256, 0, stream>>>(src, dst, base, gcur, staged);
    k_binB<<<NBUCK, 256, 0, stream>>>(staged, base, degc, esrc);

    // ---- 3 GCN layers (mm1 separate; mm2/mm3 fused into pulls) ----
    const int MMB = (N_NODES + 63) / 64;  // 1563
    k_mm<<<MMB, 256, 0, stream>>>(x, W1, dinv, H16A);
    k_pullmm<<<N_NODES / 4, 256, 0, stream>>>(H16A, esrc, base, dinv, b1, W2, H16B);
    k_pullmm<<<N_NODES / 4, 256, 0, stream>>>(H16B, esrc, base, dinv, b2, W3, H16A);
    k_pull<<<N_NODES / 4, 256, 0, stream>>>(H16A, esrc, base, dinv, b3, AGG16);

    // ---- mean pool (sorted-segment, fused counts) + head ----
    k_pool_seg<<<NB, 256, 0, stream>>>(AGG16, seg, pooled, counts);
    k_out<<<N_GRAPHS, 128, 0, stream>>>(pooled, counts, Wout, bout, out);
}

// Round 4
// 476.892 us; speedup vs baseline: 1.1309x; 1.0312x over previous
//
#include <hip/hip_runtime.h>

#define N_NODES   100000
#define N_EDGES   1600000
#define D         64
#define N_TARGETS 100
#define N_GRAPHS  512
#define NBUCK     391     // ceil(N_NODES / 256): bucket b = dst >> 8
#define EPB       4096    // edges per block in pass A

typedef _Float16 half4 __attribute__((ext_vector_type(4)));
typedef _Float16 half8 __attribute__((ext_vector_type(8)));
typedef __fp16   hf2   __attribute__((ext_vector_type(2)));   // builtin-compatible
typedef __fp16   hf8   __attribute__((ext_vector_type(8)));

#if defined(__has_builtin)
#if __has_builtin(__builtin_amdgcn_fdot2)
#define USE_DOT2 1
#endif
#endif

// ---------------- utility ----------------

__global__ void k_zero_i(int* __restrict__ p, int n) {
    int i = blockIdx.x * blockDim.x + threadIdx.x;
    if (i < n) p[i] = 0;
}

// ---- one-shot W -> fp16 conversion into conflict-free swizzled layout ----
#ifdef USE_DOT2
// layout: 32 pair-rows p (k=2p,2p+1), 64 half2 per row (col m); 16B chunk c16=m>>2
// stored at c16' = c16 ^ (p>>2). At read, p>>2 == l -> slots permute mod 8 per
// l-group -> 2-way/phase on ds_read_b128 (free, m136).
__global__ void k_prepW(const float* __restrict__ W, _Float16* __restrict__ out) {
    int t = threadIdx.x;
    int p  = t >> 3;
    int m0 = (t & 7) * 8;
    const float* r0 = W + (2 * p) * 64 + m0;
    const float* r1 = W + (2 * p + 1) * 64 + m0;
    hf2* out2 = (hf2*)out;
#pragma unroll
    for (int mm = 0; mm < 8; ++mm) {
        int m = m0 + mm;
        hf2 hv;
        hv.x = (__fp16)r0[mm];
        hv.y = (__fp16)r1[mm];
        int c16 = m >> 2;
        int idx = p * 64 + ((c16 ^ (p >> 2)) << 2) + (m & 3);
        out2[idx] = hv;
    }
}
#else
// fallback layout: row k of 64 halves; 8-half chunk c stored at c' = c ^ (k>>3)
__global__ void k_prepW(const float* __restrict__ W, _Float16* __restrict__ out) {
    int t = threadIdx.x;
#pragma unroll
    for (int it = 0; it < 2; ++it) {
        int idx = t + it * 256;       // 512 chunks
        int k = idx >> 3, c = idx & 7;
        const float* r = W + k * 64 + c * 8;
        half8 hv;
#pragma unroll
        for (int mm = 0; mm < 8; ++mm) hv[mm] = (_Float16)r[mm];
        *(half8*)&out[k * 64 + ((c ^ (k >> 3)) * 8)] = hv;
    }
}
#endif

// ---------------- CSR build ----------------

__global__ void k_deg(const int* __restrict__ dst, int* __restrict__ deg) {
    int e = blockIdx.x * blockDim.x + threadIdx.x;
    if (e < N_EDGES) atomicAdd(&deg[dst[e]], 1);
}

__global__ void k_scan1(const int* __restrict__ deg, int* __restrict__ base,
                        int* __restrict__ bsum, float* __restrict__ dinv) {
    __shared__ int s[256];
    int t = threadIdx.x, i = blockIdx.x * 256 + t;
    int v = (i < N_NODES) ? deg[i] : 0;
    if (i < N_NODES) dinv[i] = rsqrtf((float)v + 1.0f);  // +1 self-loop
    s[t] = v;
    __syncthreads();
    for (int off = 1; off < 256; off <<= 1) {
        int x = (t >= off) ? s[t - off] : 0;
        __syncthreads();
        s[t] += x;
        __syncthreads();
    }
    if (i < N_NODES) base[i] = s[t] - v;
    if (t == 255) bsum[blockIdx.x] = s[255];
}

__global__ void k_scan2(int* __restrict__ bsum, int nb) {
    __shared__ int s[512];
    int t = threadIdx.x;
    int v = (t < nb) ? bsum[t] : 0;
    s[t] = v;
    __syncthreads();
    for (int off = 1; off < 512; off <<= 1) {
        int x = (t >= off) ? s[t - off] : 0;
        __syncthreads();
        s[t] += x;
        __syncthreads();
    }
    if (t < nb) bsum[t] = s[t] - v;
}

__global__ void k_scan3(int* __restrict__ base, const int* __restrict__ bsum,
                        int* __restrict__ cursor, int* __restrict__ gcur,
                        float* __restrict__ poolz) {
    int i = blockIdx.x * blockDim.x + threadIdx.x;
    if (i < N_NODES) {
        base[i] += bsum[i >> 8];
        cursor[i] = 0;
    }
    if (i == 0) base[N_NODES] = N_EDGES;
    if (i < NBUCK) gcur[i] = 0;
    if (i < N_GRAPHS * D + N_GRAPHS) poolz[i] = 0.0f;
}

// ---- pass A: bucket edges by dst>>8 into staging at final-CSR bucket offsets ----
__global__ void __launch_bounds__(256)
k_binA(const int* __restrict__ src, const int* __restrict__ dst,
       const int* __restrict__ base, int* __restrict__ gcur,
       unsigned long long* __restrict__ staged) {
    __shared__ int hist[NBUCK];
    __shared__ int boff[NBUCK];
    int tid = threadIdx.x;
    for (int i = tid; i < NBUCK; i += 256) hist[i] = 0;
    __syncthreads();

    int e0 = blockIdx.x * EPB;
    int s_[16], d_[16], r_[16];
#pragma unroll
    for (int k = 0; k < 16; ++k) {
        int e = e0 + k * 256 + tid;
        if (e < N_EDGES) {
            s_[k] = src[e];
            d_[k] = dst[e];
            r_[k] = atomicAdd(&hist[d_[k] >> 8], 1);
        } else {
            d_[k] = -1;
        }
    }
    __syncthreads();
    for (int b = tid; b < NBUCK; b += 256) {
        int h = hist[b];
        int base_b = base[b << 8];
        boff[b] = base_b + (h > 0 ? atomicAdd(&gcur[b], h) : 0);
    }
    __syncthreads();
#pragma unroll
    for (int k = 0; k < 16; ++k) {
        if (d_[k] >= 0) {
            int b = d_[k] >> 8;
            staged[boff[b] + r_[k]] =
                ((unsigned long long)(unsigned)d_[k] << 32) | (unsigned)s_[k];
        }
    }
}

// ---- pass B: one block per bucket; L2-local cursor atomics + dense writes ----
__global__ void __launch_bounds__(256)
k_binB(const unsigned long long* __restrict__ staged, const int* __restrict__ base,
       int* __restrict__ cursor, int* __restrict__ esrc) {
    int b  = blockIdx.x;
    int n1 = (b << 8) + 256; if (n1 > N_NODES) n1 = N_NODES;
    int s0 = base[b << 8];
    int s1 = base[n1];
    for (int k = s0 + threadIdx.x; k < s1; k += 256) {
        unsigned long long pd = staged[k];
        int d = (int)(pd >> 32);
        int s = (int)(pd & 0xffffffffu);
        int pos = base[d] + atomicAdd(&cursor[d], 1);
        esrc[pos] = s;
    }
}

// ------ matmul (layer 1 only): H16[row] = fp16( X[row] @ W * dinv[row] ) ----
__global__ void __launch_bounds__(256)
k_mm(const float* __restrict__ X, const float* __restrict__ W,
     const float* __restrict__ dinv, _Float16* __restrict__ Y16) {
    __shared__ float Xs[64][68];
    __shared__ float Ws[64][68];
    int tid = threadIdx.x;
    int r0  = blockIdx.x * 64;
    {
        int lr = tid >> 4;
        int lc = (tid & 15) * 4;
#pragma unroll
        for (int i = 0; i < 4; ++i) {
            int row = lr + 16 * i;
            *(float4*)&Ws[row][lc] = *(const float4*)(W + row * 64 + lc);
            int gr = r0 + row;
            if (gr < N_NODES)
                *(float4*)&Xs[row][lc] = *(const float4*)(X + (size_t)gr * 64 + lc);
        }
    }
    __syncthreads();

    int tx = (tid & 15) * 4;
    int ty = (tid >> 4) * 4;
    float acc[4][4] = {{0.f}};

#pragma unroll
    for (int kk = 0; kk < 16; ++kk) {
        float4 a[4], w[4];
#pragma unroll
        for (int r = 0; r < 4; ++r) a[r] = *(float4*)&Xs[ty + r][kk * 4];
#pragma unroll
        for (int k = 0; k < 4; ++k) w[k] = *(float4*)&Ws[kk * 4 + k][tx];
#pragma unroll
        for (int r = 0; r < 4; ++r) {
#pragma unroll
            for (int k = 0; k < 4; ++k) {
                float av = ((const float*)&a[r])[k];
                acc[r][0] = fmaf(av, w[k].x, acc[r][0]);
                acc[r][1] = fmaf(av, w[k].y, acc[r][1]);
                acc[r][2] = fmaf(av, w[k].z, acc[r][2]);
                acc[r][3] = fmaf(av, w[k].w, acc[r][3]);
            }
        }
    }

#pragma unroll
    for (int r = 0; r < 4; ++r) {
        int gr = r0 + ty + r;
        if (gr < N_NODES) {
            float di = dinv[gr];
            half4 o;
            o.x = (_Float16)(acc[r][0] * di);
            o.y = (_Float16)(acc[r][1] * di);
            o.z = (_Float16)(acc[r][2] * di);
            o.w = (_Float16)(acc[r][3] * di);
            *(half4*)(Y16 + (size_t)gr * 64 + tx) = o;
        }
    }
}

// ---- fused pull + next-layer matmul ----
__global__ void __launch_bounds__(256)
k_pullmm(const _Float16* __restrict__ H, const int* __restrict__ esrc,
         const int* __restrict__ base, const float* __restrict__ dinv,
         const float* __restrict__ b_in, const _Float16* __restrict__ Whg,
         _Float16* __restrict__ Hout) {
    __shared__ _Float16 WhL[D * D];   // 8KB, pre-swizzled fp16 (from k_prepW)
    {
#pragma unroll
        for (int it = 0; it < 2; ++it) {
            int t = threadIdx.x + it * 256;   // 512 chunks of 8 halves
            *(half8*)&WhL[t * 8] = *(const half8*)&Whg[t * 8];
        }
    }
    __syncthreads();

    int i    = blockIdx.x * 4 + (threadIdx.x >> 6);
    int lane = threadIdx.x & 63;
    int g = lane >> 3, l = lane & 7;
    int s0 = base[i], s1 = base[i + 1];
    float acc[8] = {0.f, 0.f, 0.f, 0.f, 0.f, 0.f, 0.f, 0.f};
    if (g == 0) {
        half8 sv = *(const half8*)(H + (size_t)i * D + l * 8);
#pragma unroll
        for (int q = 0; q < 8; ++q) acc[q] = (float)sv[q];
    }

    int p = s0;
    while (p < s1) {
        int cnt = s1 - p;
        if (cnt > 64) cnt = 64;
        int ed = (lane < cnt) ? esrc[p + lane] : 0;
        int j = 0;
        for (; j + 32 <= cnt; j += 32) {
            int e0 = __shfl(ed, j + g, 64);
            int e1 = __shfl(ed, j + 8 + g, 64);
            int e2 = __shfl(ed, j + 16 + g, 64);
            int e3 = __shfl(ed, j + 24 + g, 64);
            half8 v0 = *(const half8*)(H + (size_t)e0 * D + l * 8);
            half8 v1 = *(const half8*)(H + (size_t)e1 * D + l * 8);
            half8 v2 = *(const half8*)(H + (size_t)e2 * D + l * 8);
            half8 v3 = *(const half8*)(H + (size_t)e3 * D + l * 8);
            half8 s01 = v0 + v1;   // v_pk_add_f16 (1 fp16 rounding on pair)
            half8 s23 = v2 + v3;
#pragma unroll
            for (int q = 0; q < 8; ++q)
                acc[q] += (float)s01[q] + (float)s23[q];
        }
        for (; j + 16 <= cnt; j += 16) {
            int e0 = __shfl(ed, j + g, 64);
            int e1 = __shfl(ed, j + 8 + g, 64);
            half8 v0 = *(const half8*)(H + (size_t)e0 * D + l * 8);
            half8 v1 = *(const half8*)(H + (size_t)e1 * D + l * 8);
            half8 s01 = v0 + v1;
#pragma unroll
            for (int q = 0; q < 8; ++q)
                acc[q] += (float)s01[q];
        }
        for (; j + 8 <= cnt; j += 8) {
            int e0 = __shfl(ed, j + g, 64);
            half8 v0 = *(const half8*)(H + (size_t)e0 * D + l * 8);
#pragma unroll
            for (int q = 0; q < 8; ++q) acc[q] += (float)v0[q];
        }
        if (j < cnt) {
            int idx = j + g;
            int e0 = __shfl(ed, idx & 63, 64);
            if (idx < cnt) {
                half8 v0 = *(const half8*)(H + (size_t)e0 * D + l * 8);
#pragma unroll
                for (int q = 0; q < 8; ++q) acc[q] += (float)v0[q];
            }
        }
        p += cnt;
    }
#pragma unroll
    for (int off = 8; off <= 32; off <<= 1) {
#pragma unroll
        for (int q = 0; q < 8; ++q)
            acc[q] += __shfl_xor(acc[q], off, 64);
    }

    float di = dinv[i];
    float a[8];
    {
        float4 bl0 = *(const float4*)(b_in + l * 8);
        float4 bl1 = *(const float4*)(b_in + l * 8 + 4);
        a[0] = fmaxf(fmaf(acc[0], di, bl0.x), 0.f);
        a[1] = fmaxf(fmaf(acc[1], di, bl0.y), 0.f);
        a[2] = fmaxf(fmaf(acc[2], di, bl0.z), 0.f);
        a[3] = fmaxf(fmaf(acc[3], di, bl0.w), 0.f);
        a[4] = fmaxf(fmaf(acc[4], di, bl1.x), 0.f);
        a[5] = fmaxf(fmaf(acc[5], di, bl1.y), 0.f);
        a[6] = fmaxf(fmaf(acc[6], di, bl1.z), 0.f);
        a[7] = fmaxf(fmaf(acc[7], di, bl1.w), 0.f);
    }

    float part[8] = {0.f, 0.f, 0.f, 0.f, 0.f, 0.f, 0.f, 0.f};
#ifdef USE_DOT2
    // pack activations to fp16 pairs; dot2 keeps fp32 accumulation
    hf2 a2[4];
#pragma unroll
    for (int jj = 0; jj < 4; ++jj)
        a2[jj] = __builtin_amdgcn_cvt_pkrtz(a[2 * jj], a[2 * jj + 1]);
#pragma unroll
    for (int jj = 0; jj < 4; ++jj) {
        int pr = l * 4 + jj;             // pair-row: k = 2*pr, 2*pr+1
#pragma unroll
        for (int cc = 0; cc < 2; ++cc) {
            int c16 = (g * 2 + cc) ^ l;  // swizzled 16B chunk (2-way/phase = free)
            hf8 wv = *(const hf8*)&WhL[pr * 128 + c16 * 8];  // one ds_read_b128
            hf2 w0; w0.x = wv[0]; w0.y = wv[1];
            hf2 w1; w1.x = wv[2]; w1.y = wv[3];
            hf2 w2v; w2v.x = wv[4]; w2v.y = wv[5];
            hf2 w3v; w3v.x = wv[6]; w3v.y = wv[7];
            part[cc * 4 + 0] = __builtin_amdgcn_fdot2(a2[jj], w0,  part[cc * 4 + 0], false);
            part[cc * 4 + 1] = __builtin_amdgcn_fdot2(a2[jj], w1,  part[cc * 4 + 1], false);
            part[cc * 4 + 2] = __builtin_amdgcn_fdot2(a2[jj], w2v, part[cc * 4 + 2], false);
            part[cc * 4 + 3] = __builtin_amdgcn_fdot2(a2[jj], w3v, part[cc * 4 + 3], false);
        }
    }
#else
#pragma unroll
    for (int q = 0; q < 8; ++q) {
        // chunk swizzled by l at prep time -> conflict-free ds_read_b128
        half8 wv = *(const half8*)&WhL[(l * 8 + q) * 64 + ((g ^ l) * 8)];
        float aq = a[q];
#pragma unroll
        for (int m = 0; m < 8; ++m)
            part[m] = fmaf(aq, (float)wv[m], part[m]);
    }
#endif
#pragma unroll
    for (int off = 1; off <= 4; off <<= 1) {
#pragma unroll
        for (int m = 0; m < 8; ++m)
            part[m] += __shfl_xor(part[m], off, 64);
    }
    if (l == 0) {
        half8 o;
#pragma unroll
        for (int m = 0; m < 8; ++m) o[m] = (_Float16)(part[m] * di);
        *(half8*)(Hout + (size_t)i * D + g * 8) = o;
    }
}

// ---------------- final pull (layer 3): fp16 AGG out for pooling ----------
__global__ void __launch_bounds__(256)
k_pull(const _Float16* __restrict__ H, const int* __restrict__ esrc,
       const int* __restrict__ base, const float* __restrict__ dinv,
       const float* __restrict__ b, _Float16* __restrict__ AGG16) {
    int i    = blockIdx.x * 4 + (threadIdx.x >> 6);
    int lane = threadIdx.x & 63;
    int g = lane >> 3, l = lane & 7;
    int s0 = base[i], s1 = base[i + 1];
    float acc[8] = {0.f, 0.f, 0.f, 0.f, 0.f, 0.f, 0.f, 0.f};
    if (g == 0) {
        half8 sv = *(const half8*)(H + (size_t)i * D + l * 8);
#pragma unroll
        for (int q = 0; q < 8; ++q) acc[q] = (float)sv[q];
    }

    int p = s0;
    while (p < s1) {
        int cnt = s1 - p;
        if (cnt > 64) cnt = 64;
        int ed = (lane < cnt) ? esrc[p + lane] : 0;
        int j = 0;
        for (; j + 32 <= cnt; j += 32) {
            int e0 = __shfl(ed, j + g, 64);
            int e1 = __shfl(ed, j + 8 + g, 64);
            int e2 = __shfl(ed, j + 16 + g, 64);
            int e3 = __shfl(ed, j + 24 + g, 64);
            half8 v0 = *(const half8*)(H + (size_t)e0 * D + l * 8);
            half8 v1 = *(const half8*)(H + (size_t)e1 * D + l * 8);
            half8 v2 = *(const half8*)(H + (size_t)e2 * D + l * 8);
            half8 v3 = *(const half8*)(H + (size_t)e3 * D + l * 8);
            half8 s01 = v0 + v1;
            half8 s23 = v2 + v3;
#pragma unroll
            for (int q = 0; q < 8; ++q)
                acc[q] += (float)s01[q] + (float)s23[q];
        }
        for (; j + 16 <= cnt; j += 16) {
            int e0 = __shfl(ed, j + g, 64);
            int e1 = __shfl(ed, j + 8 + g, 64);
            half8 v0 = *(const half8*)(H + (size_t)e0 * D + l * 8);
            half8 v1 = *(const half8*)(H + (size_t)e1 * D + l * 8);
            half8 s01 = v0 + v1;
#pragma unroll
            for (int q = 0; q < 8; ++q)
                acc[q] += (float)s01[q];
        }
        for (; j + 8 <= cnt; j += 8) {
            int e0 = __shfl(ed, j + g, 64);
            half8 v0 = *(const half8*)(H + (size_t)e0 * D + l * 8);
#pragma unroll
            for (int q = 0; q < 8; ++q) acc[q] += (float)v0[q];
        }
        if (j < cnt) {
            int idx = j + g;
            int e0 = __shfl(ed, idx & 63, 64);
            if (idx < cnt) {
                half8 v0 = *(const half8*)(H + (size_t)e0 * D + l * 8);
#pragma unroll
                for (int q = 0; q < 8; ++q) acc[q] += (float)v0[q];
            }
        }
        p += cnt;
    }
#pragma unroll
    for (int off = 8; off <= 32; off <<= 1) {
#pragma unroll
        for (int q = 0; q < 8; ++q)
            acc[q] += __shfl_xor(acc[q], off, 64);
    }

    if (g == 0) {
        float di = dinv[i];
        float4 bl0 = *(const float4*)(b + l * 8);
        float4 bl1 = *(const float4*)(b + l * 8 + 4);
        half8 o;
        o[0] = (_Float16)fmaf(acc[0], di, bl0.x);
        o[1] = (_Float16)fmaf(acc[1], di, bl0.y);
        o[2] = (_Float16)fmaf(acc[2], di, bl0.z);
        o[3] = (_Float16)fmaf(acc[3], di, bl0.w);
        o[4] = (_Float16)fmaf(acc[4], di, bl1.x);
        o[5] = (_Float16)fmaf(acc[5], di, bl1.y);
        o[6] = (_Float16)fmaf(acc[6], di, bl1.z);
        o[7] = (_Float16)fmaf(acc[7], di, bl1.w);
        *(half8*)(AGG16 + (size_t)i * D + l * 8) = o;
    }
}

// ---- segment-sorted pooling (fp16 in, fp32 accumulate, fused counts) ----
__global__ void __launch_bounds__(256)
k_pool_seg(const _Float16* __restrict__ H16, const int* __restrict__ seg,
           float* __restrict__ pooled, float* __restrict__ counts) {
    int wave = threadIdx.x >> 6;
    int lane = threadIdx.x & 63;
    int n0 = (blockIdx.x * 4 + wave) * 64;
    if (n0 >= N_NODES) return;
    int nEnd = n0 + 64;
    if (nEnd > N_NODES) nEnd = N_NODES;
    int cur = seg[n0];
    float acc = 0.0f;
    int run = 0;
    for (int n = n0; n < nEnd; ++n) {
        int gsg = seg[n];  // wave-uniform
        if (gsg != cur) {
            atomicAdd(&pooled[(size_t)cur * D + lane], acc);
            if (lane == 0) atomicAdd(&counts[cur], (float)run);
            acc = 0.0f; run = 0;
            cur = gsg;
        }
        acc += (float)H16[(size_t)n * D + lane];
        run += 1;
    }
    atomicAdd(&pooled[(size_t)cur * D + lane], acc);
    if (lane == 0) atomicAdd(&counts[cur], (float)run);
}

// ---------------- head ----------------
__global__ void k_out(const float* __restrict__ pooled, const float* __restrict__ counts,
                      const float* __restrict__ Wout, const float* __restrict__ bout,
                      float* __restrict__ out) {
    __shared__ float prow[D];
    int g = blockIdx.x;
    int t = threadIdx.x;
    if (t < D) prow[t] = pooled[(size_t)g * D + t] / fmaxf(counts[g], 1.0f);
    __syncthreads();
    if (t < N_TARGETS) {
        float acc = bout[t];
#pragma unroll
        for (int k = 0; k < D; ++k)
            acc = fmaf(prow[k], Wout[k * N_TARGETS + t], acc);
        out[g * N_TARGETS + t] = acc;
    }
}

// ---------------- driver ----------------

extern "C" void kernel_launch(void* const* d_in, const int* in_sizes, int n_in,
                              void* d_out, int out_size, void* d_ws, size_t ws_size,
                              hipStream_t stream) {
    const float* x    = (const float*)d_in[0];
    const float* W1   = (const float*)d_in[1];
    const float* b1   = (const float*)d_in[2];
    const float* W2   = (const float*)d_in[3];
    const float* b2   = (const float*)d_in[4];
    const float* W3   = (const float*)d_in[5];
    const float* b3   = (const float*)d_in[6];
    const float* Wout = (const float*)d_in[7];
    const float* bout = (const float*)d_in[8];
    const int*   eidx = (const int*)d_in[9];
    const int*   seg  = (const int*)d_in[10];
    const int* src = eidx;
    const int* dst = eidx + N_EDGES;
    float* out = (float*)d_out;

    // workspace layout (~33.4 MB). AGG16 aliases H16B; binA staging aliases H16A.
    _Float16* H16A   = (_Float16*)d_ws;                       // 6.4M halfs (12.8MB)
    _Float16* H16B   = H16A + (size_t)N_NODES * D;            // 6.4M halfs
    _Float16* AGG16  = H16B;                                  // alias
    unsigned long long* staged = (unsigned long long*)H16A;   // alias: 1.6M pairs
    int*      esrc   = (int*)(H16B + (size_t)N_NODES * D);    // 1.6M
    float*    dinv   = (float*)(esrc + N_EDGES);              // 100k
    int*      degc   = (int*)(dinv + N_NODES);                // 100k (deg, then cursor)
    int*      base   = degc + N_NODES;                        // 100k+1 (+pad)
    int*      bsum   = base + N_NODES + 4;                    // 512
    float*    pooled = (float*)(bsum + 512);                  // 32768
    float*    counts = pooled + N_GRAPHS * D;                 // 512
    int*      gcur   = (int*)(counts + N_GRAPHS);             // 391 (+pad to 512)
    _Float16* WhA    = (_Float16*)(gcur + 512);               // 4096 halfs (8KB)
    _Float16* WhB    = WhA + 4096;                            // 4096 halfs (8KB)

    const int NB = (N_NODES + 255) / 256;  // 391

    // ---- one-shot fp16 weight prep (swizzled layout) ----
    k_prepW<<<1, 256, 0, stream>>>(W2, WhA);
    k_prepW<<<1, 256, 0, stream>>>(W3, WhB);

    // ---- CSR build (two-pass bucketed scatter) ----
    k_zero_i<<<NB, 256, 0, stream>>>(degc, N_NODES);
    k_deg<<<N_EDGES / 256, 256, 0, stream>>>(dst, degc);
    k_scan1<<<NB, 256, 0, stream>>>(degc, base, bsum, dinv);
    k_scan2<<<1, 512, 0, stream>>>(bsum, NB);
    k_scan3<<<NB, 256, 0, stream>>>(base, bsum, degc, gcur, pooled);
    k_binA<<<(N_EDGES + EPB - 1) / EPB, 256, 0, stream>>>(src, dst, base, gcur, staged);
    k_binB<<<NBUCK, 256, 0, stream>>>(staged, base, degc, esrc);

    // ---- 3 GCN layers (mm1 separate; mm2/mm3 fused into pulls) ----
    const int MMB = (N_NODES + 63) / 64;  // 1563
    k_mm<<<MMB, 256, 0, stream>>>(x, W1, dinv, H16A);
    k_pullmm<<<N_NODES / 4, 256, 0, stream>>>(H16A, esrc, base, dinv, b1, WhA, H16B);
    k_pullmm<<<N_NODES / 4, 256, 0, stream>>>(H16B, esrc, base, dinv, b2, WhB, H16A);
    k_pull<<<N_NODES / 4, 256, 0, stream>>>(H16A, esrc, base, dinv, b3, AGG16);

    // ---- mean pool (sorted-segment, fused counts) + head ----
    k_pool_seg<<<NB, 256, 0, stream>>>(AGG16, seg, pooled, counts);
    k_out<<<N_GRAPHS, 128, 0, stream>>>(pooled, counts, Wout, bout, out);
}

// Round 5
// 460.072 us; speedup vs baseline: 1.1722x; 1.0366x over previous
//
#include <hip/hip_runtime.h>

#define N_NODES   100000
#define N_EDGES   1600000
#define D         64
#define N_TARGETS 100
#define N_GRAPHS  512
#define NBUCK     391     // ceil(N_NODES / 256): bucket b = dst >> 8
#define EPB       4096    // edges per block in pass A

typedef _Float16 half4 __attribute__((ext_vector_type(4)));
typedef _Float16 half8 __attribute__((ext_vector_type(8)));
typedef __fp16   hf2   __attribute__((ext_vector_type(2)));   // builtin-compatible
typedef __fp16   hf8   __attribute__((ext_vector_type(8)));

#if defined(__has_builtin)
#if __has_builtin(__builtin_amdgcn_fdot2)
#define USE_DOT2 1
#endif
#endif

// ---------------- utility ----------------

__global__ void k_zero_i(int* __restrict__ p, int n) {
    int i = blockIdx.x * blockDim.x + threadIdx.x;
    if (i < n) p[i] = 0;
}

// ---- one-shot W -> fp16 transposed + swizzled layout ----
// Wt[m][k]: lane m reads its row in 8-half chunks; chunk for k-range 8c..8c+7
// stored at slot c ^ (m&7): per 8-lane group slots are a permutation of 0..7
// -> ds_read_b128 spreads over the full 128B row -> conflict-free.
__global__ void k_prepW(const float* __restrict__ W, _Float16* __restrict__ out) {
    int t = threadIdx.x;
#pragma unroll
    for (int it = 0; it < 2; ++it) {
        int idx = t + it * 256;        // 512 (m, c) chunks
        int m = idx >> 3, c = idx & 7;
        half8 hv;
#pragma unroll
        for (int tt = 0; tt < 8; ++tt)
            hv[tt] = (_Float16)W[(8 * c + tt) * 64 + m];
        *(half8*)&out[m * 64 + ((c ^ (m & 7)) * 8)] = hv;
    }
}

// ---------------- CSR build ----------------

__global__ void k_deg(const int* __restrict__ dst, int* __restrict__ deg) {
    int e = blockIdx.x * blockDim.x + threadIdx.x;
    if (e < N_EDGES) atomicAdd(&deg[dst[e]], 1);
}

__global__ void k_scan1(const int* __restrict__ deg, int* __restrict__ base,
                        int* __restrict__ bsum, float* __restrict__ dinv) {
    __shared__ int s[256];
    int t = threadIdx.x, i = blockIdx.x * 256 + t;
    int v = (i < N_NODES) ? deg[i] : 0;
    if (i < N_NODES) dinv[i] = rsqrtf((float)v + 1.0f);  // +1 self-loop
    s[t] = v;
    __syncthreads();
    for (int off = 1; off < 256; off <<= 1) {
        int x = (t >= off) ? s[t - off] : 0;
        __syncthreads();
        s[t] += x;
        __syncthreads();
    }
    if (i < N_NODES) base[i] = s[t] - v;
    if (t == 255) bsum[blockIdx.x] = s[255];
}

__global__ void k_scan2(int* __restrict__ bsum, int nb) {
    __shared__ int s[512];
    int t = threadIdx.x;
    int v = (t < nb) ? bsum[t] : 0;
    s[t] = v;
    __syncthreads();
    for (int off = 1; off < 512; off <<= 1) {
        int x = (t >= off) ? s[t - off] : 0;
        __syncthreads();
        s[t] += x;
        __syncthreads();
    }
    if (t < nb) bsum[t] = s[t] - v;
}

__global__ void k_scan3(int* __restrict__ base, const int* __restrict__ bsum,
                        int* __restrict__ cursor, int* __restrict__ gcur,
                        float* __restrict__ poolz) {
    int i = blockIdx.x * blockDim.x + threadIdx.x;
    if (i < N_NODES) {
        base[i] += bsum[i >> 8];
        cursor[i] = 0;
    }
    if (i == 0) base[N_NODES] = N_EDGES;
    if (i < NBUCK) gcur[i] = 0;
    if (i < N_GRAPHS * D + N_GRAPHS) poolz[i] = 0.0f;
}

// ---- pass A: bucket edges by dst>>8 into staging at final-CSR bucket offsets ----
__global__ void __launch_bounds__(256)
k_binA(const int* __restrict__ src, const int* __restrict__ dst,
       const int* __restrict__ base, int* __restrict__ gcur,
       unsigned long long* __restrict__ staged) {
    __shared__ int hist[NBUCK];
    __shared__ int boff[NBUCK];
    int tid = threadIdx.x;
    for (int i = tid; i < NBUCK; i += 256) hist[i] = 0;
    __syncthreads();

    int e0 = blockIdx.x * EPB;
    int s_[16], d_[16], r_[16];
#pragma unroll
    for (int k = 0; k < 16; ++k) {
        int e = e0 + k * 256 + tid;
        if (e < N_EDGES) {
            s_[k] = src[e];
            d_[k] = dst[e];
            r_[k] = atomicAdd(&hist[d_[k] >> 8], 1);
        } else {
            d_[k] = -1;
        }
    }
    __syncthreads();
    for (int b = tid; b < NBUCK; b += 256) {
        int h = hist[b];
        int base_b = base[b << 8];
        boff[b] = base_b + (h > 0 ? atomicAdd(&gcur[b], h) : 0);
    }
    __syncthreads();
#pragma unroll
    for (int k = 0; k < 16; ++k) {
        if (d_[k] >= 0) {
            int b = d_[k] >> 8;
            staged[boff[b] + r_[k]] =
                ((unsigned long long)(unsigned)d_[k] << 32) | (unsigned)s_[k];
        }
    }
}

// ---- pass B: one block per bucket; L2-local cursor atomics + dense writes ----
__global__ void __launch_bounds__(256)
k_binB(const unsigned long long* __restrict__ staged, const int* __restrict__ base,
       int* __restrict__ cursor, int* __restrict__ esrc) {
    int b  = blockIdx.x;
    int n1 = (b << 8) + 256; if (n1 > N_NODES) n1 = N_NODES;
    int s0 = base[b << 8];
    int s1 = base[n1];
    for (int k = s0 + threadIdx.x; k < s1; k += 256) {
        unsigned long long pd = staged[k];
        int d = (int)(pd >> 32);
        int s = (int)(pd & 0xffffffffu);
        int pos = base[d] + atomicAdd(&cursor[d], 1);
        esrc[pos] = s;
    }
}

// ------ matmul (layer 1 only): H16[row] = fp16( X[row] @ W * dinv[row] ) ----
__global__ void __launch_bounds__(256)
k_mm(const float* __restrict__ X, const float* __restrict__ W,
     const float* __restrict__ dinv, _Float16* __restrict__ Y16) {
    __shared__ float Xs[64][68];
    __shared__ float Ws[64][68];
    int tid = threadIdx.x;
    int r0  = blockIdx.x * 64;
    {
        int lr = tid >> 4;
        int lc = (tid & 15) * 4;
#pragma unroll
        for (int i = 0; i < 4; ++i) {
            int row = lr + 16 * i;
            *(float4*)&Ws[row][lc] = *(const float4*)(W + row * 64 + lc);
            int gr = r0 + row;
            if (gr < N_NODES)
                *(float4*)&Xs[row][lc] = *(const float4*)(X + (size_t)gr * 64 + lc);
        }
    }
    __syncthreads();

    int tx = (tid & 15) * 4;
    int ty = (tid >> 4) * 4;
    float acc[4][4] = {{0.f}};

#pragma unroll
    for (int kk = 0; kk < 16; ++kk) {
        float4 a[4], w[4];
#pragma unroll
        for (int r = 0; r < 4; ++r) a[r] = *(float4*)&Xs[ty + r][kk * 4];
#pragma unroll
        for (int k = 0; k < 4; ++k) w[k] = *(float4*)&Ws[kk * 4 + k][tx];
#pragma unroll
        for (int r = 0; r < 4; ++r) {
#pragma unroll
            for (int k = 0; k < 4; ++k) {
                float av = ((const float*)&a[r])[k];
                acc[r][0] = fmaf(av, w[k].x, acc[r][0]);
                acc[r][1] = fmaf(av, w[k].y, acc[r][1]);
                acc[r][2] = fmaf(av, w[k].z, acc[r][2]);
                acc[r][3] = fmaf(av, w[k].w, acc[r][3]);
            }
        }
    }

#pragma unroll
    for (int r = 0; r < 4; ++r) {
        int gr = r0 + ty + r;
        if (gr < N_NODES) {
            float di = dinv[gr];
            half4 o;
            o.x = (_Float16)(acc[r][0] * di);
            o.y = (_Float16)(acc[r][1] * di);
            o.z = (_Float16)(acc[r][2] * di);
            o.w = (_Float16)(acc[r][3] * di);
            *(half4*)(Y16 + (size_t)gr * 64 + tx) = o;
        }
    }
}

// ---- fused pull + next-layer matmul: per-lane-feature layout ----
// lane f owns feature f (D == wave width). Gather has ZERO cross-lane reduces:
// edge index -> SGPR via readlane; row load = SGPR base + lane*2 (coalesced 128B).
// Matmul: a row -> wave-local LDS, broadcast a-chunks + swizzled Wt rows + dot2.
__global__ void __launch_bounds__(256)
k_pullmm(const _Float16* __restrict__ H, const int* __restrict__ esrc,
         const int* __restrict__ base, const float* __restrict__ dinv,
         const float* __restrict__ b_in, const _Float16* __restrict__ Whg,
         _Float16* __restrict__ Hout) {
    __shared__ _Float16 WhL[D * D];   // 8KB swizzled Wt (from k_prepW)
    __shared__ _Float16 aSh[4][D];    // per-wave activation row (128B each)
    {
#pragma unroll
        for (int it = 0; it < 2; ++it) {
            int t = threadIdx.x + it * 256;
            *(half8*)&WhL[t * 8] = *(const half8*)&Whg[t * 8];
        }
    }
    __syncthreads();

    int wv   = threadIdx.x >> 6;
    int lane = threadIdx.x & 63;
    int i    = blockIdx.x * 4 + wv;
    int s0 = base[i], s1 = base[i + 1];

    float a0 = (float)H[(size_t)i * D + lane];   // self contribution
    float a1 = 0.f, a2 = 0.f, a3 = 0.f;

    int p = s0;
    while (p < s1) {
        int cnt = s1 - p;
        if (cnt > 64) cnt = 64;
        int ed = (lane < cnt) ? esrc[p + lane] : 0;
        int j = 0;
        for (; j + 4 <= cnt; j += 4) {
            int e0 = __builtin_amdgcn_readlane(ed, j);
            int e1 = __builtin_amdgcn_readlane(ed, j + 1);
            int e2 = __builtin_amdgcn_readlane(ed, j + 2);
            int e3 = __builtin_amdgcn_readlane(ed, j + 3);
            _Float16 h0 = H[(size_t)e0 * D + lane];
            _Float16 h1 = H[(size_t)e1 * D + lane];
            _Float16 h2 = H[(size_t)e2 * D + lane];
            _Float16 h3 = H[(size_t)e3 * D + lane];
            a0 += (float)h0; a1 += (float)h1; a2 += (float)h2; a3 += (float)h3;
        }
        for (; j < cnt; ++j) {
            int e0 = __builtin_amdgcn_readlane(ed, j);
            a0 += (float)H[(size_t)e0 * D + lane];
        }
        p += cnt;
    }
    float agg = (a0 + a1) + (a2 + a3);

    float di = dinv[i];
    float av = fmaxf(fmaf(agg, di, b_in[lane]), 0.f);
    aSh[wv][lane] = (_Float16)av;
    // wave-local LDS handoff (cross-lane): drain LDS writes before reads.
    asm volatile("s_waitcnt lgkmcnt(0)" ::: "memory");

    float part = 0.f;
#pragma unroll
    for (int c = 0; c < 8; ++c) {
        hf8 a8 = *(const hf8*)&aSh[wv][c * 8];                       // broadcast: free
        hf8 w8 = *(const hf8*)&WhL[lane * 64 + ((c ^ (lane & 7)) * 8)];  // conflict-free
#ifdef USE_DOT2
#pragma unroll
        for (int q = 0; q < 4; ++q) {
            hf2 ap; ap.x = a8[2 * q]; ap.y = a8[2 * q + 1];
            hf2 wp; wp.x = w8[2 * q]; wp.y = w8[2 * q + 1];
            part = __builtin_amdgcn_fdot2(ap, wp, part, false);
        }
#else
#pragma unroll
        for (int t = 0; t < 8; ++t)
            part = fmaf((float)a8[t], (float)w8[t], part);
#endif
    }
    Hout[(size_t)i * D + lane] = (_Float16)(part * di);
}

// ---------------- final pull (layer 3): per-lane-feature, fp16 AGG out ------
__global__ void __launch_bounds__(256)
k_pull(const _Float16* __restrict__ H, const int* __restrict__ esrc,
       const int* __restrict__ base, const float* __restrict__ dinv,
       const float* __restrict__ b, _Float16* __restrict__ AGG16) {
    int wv   = threadIdx.x >> 6;
    int lane = threadIdx.x & 63;
    int i    = blockIdx.x * 4 + wv;
    int s0 = base[i], s1 = base[i + 1];

    float a0 = (float)H[(size_t)i * D + lane];
    float a1 = 0.f, a2 = 0.f, a3 = 0.f;

    int p = s0;
    while (p < s1) {
        int cnt = s1 - p;
        if (cnt > 64) cnt = 64;
        int ed = (lane < cnt) ? esrc[p + lane] : 0;
        int j = 0;
        for (; j + 4 <= cnt; j += 4) {
            int e0 = __builtin_amdgcn_readlane(ed, j);
            int e1 = __builtin_amdgcn_readlane(ed, j + 1);
            int e2 = __builtin_amdgcn_readlane(ed, j + 2);
            int e3 = __builtin_amdgcn_readlane(ed, j + 3);
            _Float16 h0 = H[(size_t)e0 * D + lane];
            _Float16 h1 = H[(size_t)e1 * D + lane];
            _Float16 h2 = H[(size_t)e2 * D + lane];
            _Float16 h3 = H[(size_t)e3 * D + lane];
            a0 += (float)h0; a1 += (float)h1; a2 += (float)h2; a3 += (float)h3;
        }
        for (; j < cnt; ++j) {
            int e0 = __builtin_amdgcn_readlane(ed, j);
            a0 += (float)H[(size_t)e0 * D + lane];
        }
        p += cnt;
    }
    float agg = (a0 + a1) + (a2 + a3);
    float di = dinv[i];
    AGG16[(size_t)i * D + lane] = (_Float16)fmaf(agg, di, b[lane]);
}

// ---- segment-sorted pooling (fp16 in, fp32 accumulate, fused counts) ----
__global__ void __launch_bounds__(256)
k_pool_seg(const _Float16* __restrict__ H16, const int* __restrict__ seg,
           float* __restrict__ pooled, float* __restrict__ counts) {
    int wave = threadIdx.x >> 6;
    int lane = threadIdx.x & 63;
    int n0 = (blockIdx.x * 4 + wave) * 64;
    if (n0 >= N_NODES) return;
    int nEnd = n0 + 64;
    if (nEnd > N_NODES) nEnd = N_NODES;
    int cur = seg[n0];
    float acc = 0.0f;
    int run = 0;
    for (int n = n0; n < nEnd; ++n) {
        int gsg = seg[n];  // wave-uniform
        if (gsg != cur) {
            atomicAdd(&pooled[(size_t)cur * D + lane], acc);
            if (lane == 0) atomicAdd(&counts[cur], (float)run);
            acc = 0.0f; run = 0;
            cur = gsg;
        }
        acc += (float)H16[(size_t)n * D + lane];
        run += 1;
    }
    atomicAdd(&pooled[(size_t)cur * D + lane], acc);
    if (lane == 0) atomicAdd(&counts[cur], (float)run);
}

// ---------------- head ----------------
__global__ void k_out(const float* __restrict__ pooled, const float* __restrict__ counts,
                      const float* __restrict__ Wout, const float* __restrict__ bout,
                      float* __restrict__ out) {
    __shared__ float prow[D];
    int g = blockIdx.x;
    int t = threadIdx.x;
    if (t < D) prow[t] = pooled[(size_t)g * D + t] / fmaxf(counts[g], 1.0f);
    __syncthreads();
    if (t < N_TARGETS) {
        float acc = bout[t];
#pragma unroll
        for (int k = 0; k < D; ++k)
            acc = fmaf(prow[k], Wout[k * N_TARGETS + t], acc);
        out[g * N_TARGETS + t] = acc;
    }
}

// ---------------- driver ----------------

extern "C" void kernel_launch(void* const* d_in, const int* in_sizes, int n_in,
                              void* d_out, int out_size, void* d_ws, size_t ws_size,
                              hipStream_t stream) {
    const float* x    = (const float*)d_in[0];
    const float* W1   = (const float*)d_in[1];
    const float* b1   = (const float*)d_in[2];
    const float* W2   = (const float*)d_in[3];
    const float* b2   = (const float*)d_in[4];
    const float* W3   = (const float*)d_in[5];
    const float* b3   = (const float*)d_in[6];
    const float* Wout = (const float*)d_in[7];
    const float* bout = (const float*)d_in[8];
    const int*   eidx = (const int*)d_in[9];
    const int*   seg  = (const int*)d_in[10];
    const int* src = eidx;
    const int* dst = eidx + N_EDGES;
    float* out = (float*)d_out;

    // workspace layout (~33.4 MB). AGG16 aliases H16B; binA staging aliases H16A.
    _Float16* H16A   = (_Float16*)d_ws;                       // 6.4M halfs (12.8MB)
    _Float16* H16B   = H16A + (size_t)N_NODES * D;            // 6.4M halfs
    _Float16* AGG16  = H16B;                                  // alias
    unsigned long long* staged = (unsigned long long*)H16A;   // alias: 1.6M pairs
    int*      esrc   = (int*)(H16B + (size_t)N_NODES * D);    // 1.6M
    float*    dinv   = (float*)(esrc + N_EDGES);              // 100k
    int*      degc   = (int*)(dinv + N_NODES);                // 100k (deg, then cursor)
    int*      base   = degc + N_NODES;                        // 100k+1 (+pad)
    int*      bsum   = base + N_NODES + 4;                    // 512
    float*    pooled = (float*)(bsum + 512);                  // 32768
    float*    counts = pooled + N_GRAPHS * D;                 // 512
    int*      gcur   = (int*)(counts + N_GRAPHS);             // 391 (+pad to 512)
    _Float16* WhA    = (_Float16*)(gcur + 512);               // 4096 halfs (8KB)
    _Float16* WhB    = WhA + 4096;                            // 4096 halfs (8KB)

    const int NB = (N_NODES + 255) / 256;  // 391

    // ---- one-shot fp16 weight prep (transposed + swizzled layout) ----
    k_prepW<<<1, 256, 0, stream>>>(W2, WhA);
    k_prepW<<<1, 256, 0, stream>>>(W3, WhB);

    // ---- CSR build (two-pass bucketed scatter) ----
    k_zero_i<<<NB, 256, 0, stream>>>(degc, N_NODES);
    k_deg<<<N_EDGES / 256, 256, 0, stream>>>(dst, degc);
    k_scan1<<<NB, 256, 0, stream>>>(degc, base, bsum, dinv);
    k_scan2<<<1, 512, 0, stream>>>(bsum, NB);
    k_scan3<<<NB, 256, 0, stream>>>(base, bsum, degc, gcur, pooled);
    k_binA<<<(N_EDGES + EPB - 1) / EPB, 256, 0, stream>>>(src, dst, base, gcur, staged);
    k_binB<<<NBUCK, 256, 0, stream>>>(staged, base, degc, esrc);

    // ---- 3 GCN layers (mm1 separate; mm2/mm3 fused into pulls) ----
    const int MMB = (N_NODES + 63) / 64;  // 1563
    k_mm<<<MMB, 256, 0, stream>>>(x, W1, dinv, H16A);
    k_pullmm<<<N_NODES / 4, 256, 0, stream>>>(H16A, esrc, base, dinv, b1, WhA, H16B);
    k_pullmm<<<N_NODES / 4, 256, 0, stream>>>(H16B, esrc, base, dinv, b2, WhB, H16A);
    k_pull<<<N_NODES / 4, 256, 0, stream>>>(H16A, esrc, base, dinv, b3, AGG16);

    // ---- mean pool (sorted-segment, fused counts) + head ----
    k_pool_seg<<<NB, 256, 0, stream>>>(AGG16, seg, pooled, counts);
    k_out<<<N_GRAPHS, 128, 0, stream>>>(pooled, counts, Wout, bout, out);
}

// Round 6
// 449.641 us; speedup vs baseline: 1.1994x; 1.0232x over previous
//
#include <hip/hip_runtime.h>

#define N_NODES   100000
#define N_EDGES   1600000
#define D         64
#define N_TARGETS 100
#define N_GRAPHS  512
#define NBUCK     391     // ceil(N_NODES / 256): bucket b = dst >> 8
#define EPB       4096    // edges per block in pass A
#define MM_NPW    16      // nodes per wave in k_mm

typedef _Float16 half4 __attribute__((ext_vector_type(4)));
typedef _Float16 half8 __attribute__((ext_vector_type(8)));
typedef __fp16   hf2   __attribute__((ext_vector_type(2)));   // builtin-compatible
typedef __fp16   hf8   __attribute__((ext_vector_type(8)));

#if defined(__has_builtin)
#if __has_builtin(__builtin_amdgcn_fdot2)
#define USE_DOT2 1
#endif
#endif

// ---------------- utility ----------------

__global__ void k_zero_i(int* __restrict__ p, int n) {
    int i = blockIdx.x * blockDim.x + threadIdx.x;
    if (i < n) p[i] = 0;
}

// ---- one-shot W -> fp16 transposed + swizzled layout (for k_pullmm) ----
// Wt[m][k]: lane m reads its row in 8-half chunks; chunk for k-range 8c..8c+7
// stored at slot c ^ (m&7) -> conflict-free ds_read_b128.
__global__ void k_prepW(const float* __restrict__ W, _Float16* __restrict__ out) {
    int t = threadIdx.x;
#pragma unroll
    for (int it = 0; it < 2; ++it) {
        int idx = t + it * 256;        // 512 (m, c) chunks
        int m = idx >> 3, c = idx & 7;
        half8 hv;
#pragma unroll
        for (int tt = 0; tt < 8; ++tt)
            hv[tt] = (_Float16)W[(8 * c + tt) * 64 + m];
        *(half8*)&out[m * 64 + ((c ^ (m & 7)) * 8)] = hv;
    }
}

// ---------------- CSR build ----------------

__global__ void k_deg(const int* __restrict__ dst, int* __restrict__ deg) {
    int e = blockIdx.x * blockDim.x + threadIdx.x;
    if (e < N_EDGES) atomicAdd(&deg[dst[e]], 1);
}

__global__ void k_scan1(const int* __restrict__ deg, int* __restrict__ base,
                        int* __restrict__ bsum, float* __restrict__ dinv) {
    __shared__ int s[256];
    int t = threadIdx.x, i = blockIdx.x * 256 + t;
    int v = (i < N_NODES) ? deg[i] : 0;
    if (i < N_NODES) dinv[i] = rsqrtf((float)v + 1.0f);  // +1 self-loop
    s[t] = v;
    __syncthreads();
    for (int off = 1; off < 256; off <<= 1) {
        int x = (t >= off) ? s[t - off] : 0;
        __syncthreads();
        s[t] += x;
        __syncthreads();
    }
    if (i < N_NODES) base[i] = s[t] - v;
    if (t == 255) bsum[blockIdx.x] = s[255];
}

__global__ void k_scan2(int* __restrict__ bsum, int nb) {
    __shared__ int s[512];
    int t = threadIdx.x;
    int v = (t < nb) ? bsum[t] : 0;
    s[t] = v;
    __syncthreads();
    for (int off = 1; off < 512; off <<= 1) {
        int x = (t >= off) ? s[t - off] : 0;
        __syncthreads();
        s[t] += x;
        __syncthreads();
    }
    if (t < nb) bsum[t] = s[t] - v;
}

__global__ void k_scan3(int* __restrict__ base, const int* __restrict__ bsum,
                        int* __restrict__ cursor, int* __restrict__ gcur,
                        float* __restrict__ poolz) {
    int i = blockIdx.x * blockDim.x + threadIdx.x;
    if (i < N_NODES) {
        base[i] += bsum[i >> 8];
        cursor[i] = 0;
    }
    if (i == 0) base[N_NODES] = N_EDGES;
    if (i < NBUCK) gcur[i] = 0;
    if (i < N_GRAPHS * D + N_GRAPHS) poolz[i] = 0.0f;
}

// ---- pass A: bucket edges by dst>>8 into staging at final-CSR bucket offsets ----
__global__ void __launch_bounds__(256)
k_binA(const int* __restrict__ src, const int* __restrict__ dst,
       const int* __restrict__ base, int* __restrict__ gcur,
       unsigned long long* __restrict__ staged) {
    __shared__ int hist[NBUCK];
    __shared__ int boff[NBUCK];
    int tid = threadIdx.x;
    for (int i = tid; i < NBUCK; i += 256) hist[i] = 0;
    __syncthreads();

    int e0 = blockIdx.x * EPB;
    int s_[16], d_[16], r_[16];
#pragma unroll
    for (int k = 0; k < 16; ++k) {
        int e = e0 + k * 256 + tid;
        if (e < N_EDGES) {
            s_[k] = src[e];
            d_[k] = dst[e];
            r_[k] = atomicAdd(&hist[d_[k] >> 8], 1);
        } else {
            d_[k] = -1;
        }
    }
    __syncthreads();
    for (int b = tid; b < NBUCK; b += 256) {
        int h = hist[b];
        int base_b = base[b << 8];
        boff[b] = base_b + (h > 0 ? atomicAdd(&gcur[b], h) : 0);
    }
    __syncthreads();
#pragma unroll
    for (int k = 0; k < 16; ++k) {
        if (d_[k] >= 0) {
            int b = d_[k] >> 8;
            staged[boff[b] + r_[k]] =
                ((unsigned long long)(unsigned)d_[k] << 32) | (unsigned)s_[k];
        }
    }
}

// ---- pass B: one block per bucket; L2-local cursor atomics + dense writes ----
__global__ void __launch_bounds__(256)
k_binB(const unsigned long long* __restrict__ staged, const int* __restrict__ base,
       int* __restrict__ cursor, int* __restrict__ esrc) {
    int b  = blockIdx.x;
    int n1 = (b << 8) + 256; if (n1 > N_NODES) n1 = N_NODES;
    int s0 = base[b << 8];
    int s1 = base[n1];
    for (int k = s0 + threadIdx.x; k < s1; k += 256) {
        unsigned long long pd = staged[k];
        int d = (int)(pd >> 32);
        int s = (int)(pd & 0xffffffffu);
        int pos = base[d] + atomicAdd(&cursor[d], 1);
        esrc[pos] = s;
    }
}

// ------ matmul (layer 1): per-lane-feature, W1 column in registers ----------
// Lane m owns output feature m. W1 column m (64 floats) lives in VGPRs, filled
// once per wave from LDS (column read = 2-way bank spread = free). Per node:
// coalesced X-row load -> wave-local LDS -> broadcast float4 reads + 64 fma
// (4 independent chains). fp32 throughout. Fixes R4's 248-VGPR/9.5%-occ kernel.
__global__ void __launch_bounds__(256)
k_mm(const float* __restrict__ X, const float* __restrict__ W,
     const float* __restrict__ dinv, _Float16* __restrict__ Y16) {
    __shared__ float W1L[D * D];   // 16 KB raw [k][m]
    __shared__ float aSh[4][D];    // per-wave X row
    int tid = threadIdx.x;
#pragma unroll
    for (int it = 0; it < 4; ++it) {
        int idx = (tid + it * 256) * 4;
        *(float4*)&W1L[idx] = *(const float4*)(W + idx);
    }
    __syncthreads();

    int wv = tid >> 6, lane = tid & 63;
    float wreg[D];   // W1[k][lane] for all k
#pragma unroll
    for (int k = 0; k < D; ++k)
        wreg[k] = W1L[k * D + lane];

    int i0 = (blockIdx.x * 4 + wv) * MM_NPW;
    if (i0 >= N_NODES) return;
    int iEnd = i0 + MM_NPW; if (iEnd > N_NODES) iEnd = N_NODES;

    float xv = X[(size_t)i0 * D + lane];
    for (int i = i0; i < iEnd; ++i) {
        // prefetch next node's X under this node's compute
        int inext = (i + 1 < N_NODES) ? (i + 1) : i;
        float xnext = X[(size_t)inext * D + lane];

        aSh[wv][lane] = xv;
        asm volatile("s_waitcnt lgkmcnt(0)" ::: "memory");

        float ac0 = 0.f, ac1 = 0.f, ac2 = 0.f, ac3 = 0.f;
#pragma unroll
        for (int c = 0; c < 16; ++c) {
            float4 a4 = *(const float4*)&aSh[wv][c * 4];
            ac0 = fmaf(a4.x, wreg[4 * c + 0], ac0);
            ac1 = fmaf(a4.y, wreg[4 * c + 1], ac1);
            ac2 = fmaf(a4.z, wreg[4 * c + 2], ac2);
            ac3 = fmaf(a4.w, wreg[4 * c + 3], ac3);
        }
        float acc = (ac0 + ac1) + (ac2 + ac3);
        Y16[(size_t)i * D + lane] = (_Float16)(acc * dinv[i]);
        xv = xnext;
    }
}

// ---- fused pull + next-layer matmul: per-lane-feature layout ----
__global__ void __launch_bounds__(256)
k_pullmm(const _Float16* __restrict__ H, const int* __restrict__ esrc,
         const int* __restrict__ base, const float* __restrict__ dinv,
         const float* __restrict__ b_in, const _Float16* __restrict__ Whg,
         _Float16* __restrict__ Hout) {
    __shared__ _Float16 WhL[D * D];   // 8KB swizzled Wt (from k_prepW)
    __shared__ _Float16 aSh[4][D];    // per-wave activation row (128B each)
    {
#pragma unroll
        for (int it = 0; it < 2; ++it) {
            int t = threadIdx.x + it * 256;
            *(half8*)&WhL[t * 8] = *(const half8*)&Whg[t * 8];
        }
    }
    __syncthreads();

    int wv   = threadIdx.x >> 6;
    int lane = threadIdx.x & 63;
    int i    = blockIdx.x * 4 + wv;
    int s0 = base[i], s1 = base[i + 1];

    float a0 = (float)H[(size_t)i * D + lane];   // self contribution
    float a1 = 0.f, a2 = 0.f, a3 = 0.f;

    int p = s0;
    while (p < s1) {
        int cnt = s1 - p;
        if (cnt > 64) cnt = 64;
        int ed = (lane < cnt) ? esrc[p + lane] : 0;
        int j = 0;
        for (; j + 4 <= cnt; j += 4) {
            int e0 = __builtin_amdgcn_readlane(ed, j);
            int e1 = __builtin_amdgcn_readlane(ed, j + 1);
            int e2 = __builtin_amdgcn_readlane(ed, j + 2);
            int e3 = __builtin_amdgcn_readlane(ed, j + 3);
            _Float16 h0 = H[(size_t)e0 * D + lane];
            _Float16 h1 = H[(size_t)e1 * D + lane];
            _Float16 h2 = H[(size_t)e2 * D + lane];
            _Float16 h3 = H[(size_t)e3 * D + lane];
            a0 += (float)h0; a1 += (float)h1; a2 += (float)h2; a3 += (float)h3;
        }
        for (; j < cnt; ++j) {
            int e0 = __builtin_amdgcn_readlane(ed, j);
            a0 += (float)H[(size_t)e0 * D + lane];
        }
        p += cnt;
    }
    float agg = (a0 + a1) + (a2 + a3);

    float di = dinv[i];
    float av = fmaxf(fmaf(agg, di, b_in[lane]), 0.f);
    aSh[wv][lane] = (_Float16)av;
    asm volatile("s_waitcnt lgkmcnt(0)" ::: "memory");

    float part = 0.f;
#pragma unroll
    for (int c = 0; c < 8; ++c) {
        hf8 a8 = *(const hf8*)&aSh[wv][c * 8];                           // broadcast
        hf8 w8 = *(const hf8*)&WhL[lane * 64 + ((c ^ (lane & 7)) * 8)];  // conflict-free
#ifdef USE_DOT2
#pragma unroll
        for (int q = 0; q < 4; ++q) {
            hf2 ap; ap.x = a8[2 * q]; ap.y = a8[2 * q + 1];
            hf2 wp; wp.x = w8[2 * q]; wp.y = w8[2 * q + 1];
            part = __builtin_amdgcn_fdot2(ap, wp, part, false);
        }
#else
#pragma unroll
        for (int t = 0; t < 8; ++t)
            part = fmaf((float)a8[t], (float)w8[t], part);
#endif
    }
    Hout[(size_t)i * D + lane] = (_Float16)(part * di);
}

// ---------------- final pull (layer 3): per-lane-feature, fp16 AGG out ------
__global__ void __launch_bounds__(256)
k_pull(const _Float16* __restrict__ H, const int* __restrict__ esrc,
       const int* __restrict__ base, const float* __restrict__ dinv,
       const float* __restrict__ b, _Float16* __restrict__ AGG16) {
    int wv   = threadIdx.x >> 6;
    int lane = threadIdx.x & 63;
    int i    = blockIdx.x * 4 + wv;
    int s0 = base[i], s1 = base[i + 1];

    float a0 = (float)H[(size_t)i * D + lane];
    float a1 = 0.f, a2 = 0.f, a3 = 0.f;

    int p = s0;
    while (p < s1) {
        int cnt = s1 - p;
        if (cnt > 64) cnt = 64;
        int ed = (lane < cnt) ? esrc[p + lane] : 0;
        int j = 0;
        for (; j + 4 <= cnt; j += 4) {
            int e0 = __builtin_amdgcn_readlane(ed, j);
            int e1 = __builtin_amdgcn_readlane(ed, j + 1);
            int e2 = __builtin_amdgcn_readlane(ed, j + 2);
            int e3 = __builtin_amdgcn_readlane(ed, j + 3);
            _Float16 h0 = H[(size_t)e0 * D + lane];
            _Float16 h1 = H[(size_t)e1 * D + lane];
            _Float16 h2 = H[(size_t)e2 * D + lane];
            _Float16 h3 = H[(size_t)e3 * D + lane];
            a0 += (float)h0; a1 += (float)h1; a2 += (float)h2; a3 += (float)h3;
        }
        for (; j < cnt; ++j) {
            int e0 = __builtin_amdgcn_readlane(ed, j);
            a0 += (float)H[(size_t)e0 * D + lane];
        }
        p += cnt;
    }
    float agg = (a0 + a1) + (a2 + a3);
    float di = dinv[i];
    AGG16[(size_t)i * D + lane] = (_Float16)fmaf(agg, di, b[lane]);
}

// ---- segment-sorted pooling (fp16 in, fp32 accumulate, fused counts) ----
__global__ void __launch_bounds__(256)
k_pool_seg(const _Float16* __restrict__ H16, const int* __restrict__ seg,
           float* __restrict__ pooled, float* __restrict__ counts) {
    int wave = threadIdx.x >> 6;
    int lane = threadIdx.x & 63;
    int n0 = (blockIdx.x * 4 + wave) * 64;
    if (n0 >= N_NODES) return;
    int nEnd = n0 + 64;
    if (nEnd > N_NODES) nEnd = N_NODES;
    int cur = seg[n0];
    float acc = 0.0f;
    int run = 0;
    for (int n = n0; n < nEnd; ++n) {
        int gsg = seg[n];  // wave-uniform
        if (gsg != cur) {
            atomicAdd(&pooled[(size_t)cur * D + lane], acc);
            if (lane == 0) atomicAdd(&counts[cur], (float)run);
            acc = 0.0f; run = 0;
            cur = gsg;
        }
        acc += (float)H16[(size_t)n * D + lane];
        run += 1;
    }
    atomicAdd(&pooled[(size_t)cur * D + lane], acc);
    if (lane == 0) atomicAdd(&counts[cur], (float)run);
}

// ---------------- head ----------------
__global__ void k_out(const float* __restrict__ pooled, const float* __restrict__ counts,
                      const float* __restrict__ Wout, const float* __restrict__ bout,
                      float* __restrict__ out) {
    __shared__ float prow[D];
    int g = blockIdx.x;
    int t = threadIdx.x;
    if (t < D) prow[t] = pooled[(size_t)g * D + t] / fmaxf(counts[g], 1.0f);
    __syncthreads();
    if (t < N_TARGETS) {
        float acc = bout[t];
#pragma unroll
        for (int k = 0; k < D; ++k)
            acc = fmaf(prow[k], Wout[k * N_TARGETS + t], acc);
        out[g * N_TARGETS + t] = acc;
    }
}

// ---------------- driver ----------------

extern "C" void kernel_launch(void* const* d_in, const int* in_sizes, int n_in,
                              void* d_out, int out_size, void* d_ws, size_t ws_size,
                              hipStream_t stream) {
    const float* x    = (const float*)d_in[0];
    const float* W1   = (const float*)d_in[1];
    const float* b1   = (const float*)d_in[2];
    const float* W2   = (const float*)d_in[3];
    const float* b2   = (const float*)d_in[4];
    const float* W3   = (const float*)d_in[5];
    const float* b3   = (const float*)d_in[6];
    const float* Wout = (const float*)d_in[7];
    const float* bout = (const float*)d_in[8];
    const int*   eidx = (const int*)d_in[9];
    const int*   seg  = (const int*)d_in[10];
    const int* src = eidx;
    const int* dst = eidx + N_EDGES;
    float* out = (float*)d_out;

    // workspace layout (~33.4 MB). AGG16 aliases H16B; binA staging aliases H16A.
    _Float16* H16A   = (_Float16*)d_ws;                       // 6.4M halfs (12.8MB)
    _Float16* H16B   = H16A + (size_t)N_NODES * D;            // 6.4M halfs
    _Float16* AGG16  = H16B;                                  // alias
    unsigned long long* staged = (unsigned long long*)H16A;   // alias: 1.6M pairs
    int*      esrc   = (int*)(H16B + (size_t)N_NODES * D);    // 1.6M
    float*    dinv   = (float*)(esrc + N_EDGES);              // 100k
    int*      degc   = (int*)(dinv + N_NODES);                // 100k (deg, then cursor)
    int*      base   = degc + N_NODES;                        // 100k+1 (+pad)
    int*      bsum   = base + N_NODES + 4;                    // 512
    float*    pooled = (float*)(bsum + 512);                  // 32768
    float*    counts = pooled + N_GRAPHS * D;                 // 512
    int*      gcur   = (int*)(counts + N_GRAPHS);             // 391 (+pad to 512)
    _Float16* WhA    = (_Float16*)(gcur + 512);               // 4096 halfs (8KB)
    _Float16* WhB    = WhA + 4096;                            // 4096 halfs (8KB)

    const int NB = (N_NODES + 255) / 256;  // 391

    // ---- one-shot fp16 weight prep (transposed + swizzled layout) ----
    k_prepW<<<1, 256, 0, stream>>>(W2, WhA);
    k_prepW<<<1, 256, 0, stream>>>(W3, WhB);

    // ---- CSR build (two-pass bucketed scatter) ----
    k_zero_i<<<NB, 256, 0, stream>>>(degc, N_NODES);
    k_deg<<<N_EDGES / 256, 256, 0, stream>>>(dst, degc);
    k_scan1<<<NB, 256, 0, stream>>>(degc, base, bsum, dinv);
    k_scan2<<<1, 512, 0, stream>>>(bsum, NB);
    k_scan3<<<NB, 256, 0, stream>>>(base, bsum, degc, gcur, pooled);
    k_binA<<<(N_EDGES + EPB - 1) / EPB, 256, 0, stream>>>(src, dst, base, gcur, staged);
    k_binB<<<NBUCK, 256, 0, stream>>>(staged, base, degc, esrc);

    // ---- 3 GCN layers (mm1 separate; mm2/mm3 fused into pulls) ----
    const int MMB = (N_NODES + 4 * MM_NPW - 1) / (4 * MM_NPW);  // 1563
    k_mm<<<MMB, 256, 0, stream>>>(x, W1, dinv, H16A);
    k_pullmm<<<N_NODES / 4, 256, 0, stream>>>(H16A, esrc, base, dinv, b1, WhA, H16B);
    k_pullmm<<<N_NODES / 4, 256, 0, stream>>>(H16B, esrc, base, dinv, b2, WhB, H16A);
    k_pull<<<N_NODES / 4, 256, 0, stream>>>(H16A, esrc, base, dinv, b3, AGG16);

    // ---- mean pool (sorted-segment, fused counts) + head ----
    k_pool_seg<<<NB, 256, 0, stream>>>(AGG16, seg, pooled, counts);
    k_out<<<N_GRAPHS, 128, 0, stream>>>(pooled, counts, Wout, bout, out);
}

// Round 7
// 357.114 us; speedup vs baseline: 1.5102x; 1.2591x over previous
//
#include <hip/hip_runtime.h>

#define N_NODES   100000
#define N_EDGES   1600000
#define D         64
#define N_TARGETS 100
#define N_GRAPHS  512
#define NBUCK     391     // ceil(N_NODES / 256): bucket b = dst >> 8
#define EPB       4096    // edges per block in pass A
#define BCAP      6144    // bucket slab capacity (Poisson(4096) + 32 sigma)
#define MM_NPW    16      // nodes per wave in k_mm

typedef _Float16 half4 __attribute__((ext_vector_type(4)));
typedef _Float16 half8 __attribute__((ext_vector_type(8)));
typedef __fp16   hf2   __attribute__((ext_vector_type(2)));   // builtin-compatible
typedef __fp16   hf8   __attribute__((ext_vector_type(8)));

#if defined(__has_builtin)
#if __has_builtin(__builtin_amdgcn_fdot2)
#define USE_DOT2 1
#endif
#endif

// ---- init: zero bucket cursors + pooled/counts ----
__global__ void k_init(int* __restrict__ gcur, float* __restrict__ poolz) {
    int i = blockIdx.x * blockDim.x + threadIdx.x;
    if (i < NBUCK) gcur[i] = 0;
    if (i < N_GRAPHS * D + N_GRAPHS) poolz[i] = 0.0f;
}

// ---- one-shot W -> fp16 transposed + swizzled layout (for k_pullmm) ----
// Wt[m][k]: lane m reads its row in 8-half chunks; chunk for k-range 8c..8c+7
// stored at slot c ^ (m&7) -> conflict-free ds_read_b128.
__global__ void k_prepW(const float* __restrict__ W, _Float16* __restrict__ out) {
    int t = threadIdx.x;
#pragma unroll
    for (int it = 0; it < 2; ++it) {
        int idx = t + it * 256;        // 512 (m, c) chunks
        int m = idx >> 3, c = idx & 7;
        half8 hv;
#pragma unroll
        for (int tt = 0; tt < 8; ++tt)
            hv[tt] = (_Float16)W[(8 * c + tt) * 64 + m];
        *(half8*)&out[m * 64 + ((c ^ (m & 7)) * 8)] = hv;
    }
}

// ---- pass A: bucket edges by dst>>8 into fixed-capacity slabs ----
// No degree pre-pass needed: slab offset via one global atomic per (block,bucket).
__global__ void __launch_bounds__(256)
k_binA(const int* __restrict__ src, const int* __restrict__ dst,
       int* __restrict__ gcur, unsigned long long* __restrict__ staged) {
    __shared__ int hist[NBUCK];
    __shared__ int boff[NBUCK];
    int tid = threadIdx.x;
    for (int i = tid; i < NBUCK; i += 256) hist[i] = 0;
    __syncthreads();

    int e0 = blockIdx.x * EPB;
    int s_[16], d_[16], r_[16];
#pragma unroll
    for (int k = 0; k < 16; ++k) {
        int e = e0 + k * 256 + tid;
        if (e < N_EDGES) {
            s_[k] = src[e];
            d_[k] = dst[e];
            r_[k] = atomicAdd(&hist[d_[k] >> 8], 1);
        } else {
            d_[k] = -1;
        }
    }
    __syncthreads();
    for (int b = tid; b < NBUCK; b += 256) {
        int h = hist[b];
        boff[b] = (h > 0) ? atomicAdd(&gcur[b], h) : 0;
    }
    __syncthreads();
#pragma unroll
    for (int k = 0; k < 16; ++k) {
        if (d_[k] >= 0) {
            int b = d_[k] >> 8;
            staged[(size_t)b * BCAP + boff[b] + r_[k]] =
                ((unsigned long long)(unsigned)d_[k] << 32) | (unsigned)s_[k];
        }
    }
}

// ---- scan bucket totals -> bucket edge-space starts (one tiny block) ----
__global__ void k_scanB(const int* __restrict__ gcur, int* __restrict__ bstart) {
    __shared__ int s[512];
    int t = threadIdx.x;
    int v = (t < NBUCK) ? gcur[t] : 0;
    s[t] = v;
    __syncthreads();
    for (int off = 1; off < 512; off <<= 1) {
        int x = (t >= off) ? s[t - off] : 0;
        __syncthreads();
        s[t] += x;
        __syncthreads();
    }
    if (t < NBUCK) bstart[t] = s[t] - v;
    if (t == 0) bstart[NBUCK] = N_EDGES;
}

// ---- pass B: one block per bucket. LDS degree-count -> LDS prefix scan ->
// write base+dinv for its 256 nodes -> place esrc (all L2-local, line-dense).
// Replaces k_deg (66us of atomic write-amp) + k_scan1/2/3 entirely.
__global__ void __launch_bounds__(256)
k_binB(const unsigned long long* __restrict__ staged, const int* __restrict__ gcur,
       const int* __restrict__ bstart, int* __restrict__ esrc,
       int* __restrict__ base, float* __restrict__ dinv) {
    __shared__ int s[256];
    __shared__ int lbase[256];
    __shared__ int cur[256];
    int b = blockIdx.x;
    int t = threadIdx.x;
    int n0 = b << 8;
    int Eb = gcur[b];
    int Sb = bstart[b];
    const unsigned long long* sl = staged + (size_t)b * BCAP;

    cur[t] = 0;   // pass-1 counters
    __syncthreads();
    for (int k = t; k < Eb; k += 256) {
        int dl = ((int)(sl[k] >> 32)) & 255;
        atomicAdd(&cur[dl], 1);
    }
    __syncthreads();
    int v = cur[t];
    s[t] = v;
    __syncthreads();
    for (int off = 1; off < 256; off <<= 1) {
        int x = (t >= off) ? s[t - off] : 0;
        __syncthreads();
        s[t] += x;
        __syncthreads();
    }
    lbase[t] = s[t] - v;
    int gi = n0 + t;
    if (gi < N_NODES) {
        base[gi] = Sb + (s[t] - v);
        dinv[gi] = rsqrtf((float)v + 1.0f);   // +1 self-loop
    }
    if (b == 0 && t == 0) base[N_NODES] = N_EDGES;
    cur[t] = 0;   // pass-2 cursors
    __syncthreads();
    for (int k = t; k < Eb; k += 256) {
        unsigned long long pd = sl[k];
        int dl = ((int)(pd >> 32)) & 255;
        int pos = Sb + lbase[dl] + atomicAdd(&cur[dl], 1);
        esrc[pos] = (int)(pd & 0xffffffffu);
    }
}

// ------ matmul (layer 1): per-lane-feature, W1 column in registers ----------
__global__ void __launch_bounds__(256)
k_mm(const float* __restrict__ X, const float* __restrict__ W,
     const float* __restrict__ dinv, _Float16* __restrict__ Y16) {
    __shared__ float W1L[D * D];   // 16 KB raw [k][m]
    __shared__ float aSh[4][D];    // per-wave X row
    int tid = threadIdx.x;
#pragma unroll
    for (int it = 0; it < 4; ++it) {
        int idx = (tid + it * 256) * 4;
        *(float4*)&W1L[idx] = *(const float4*)(W + idx);
    }
    __syncthreads();

    int wv = tid >> 6, lane = tid & 63;
    float wreg[D];   // W1[k][lane] for all k
#pragma unroll
    for (int k = 0; k < D; ++k)
        wreg[k] = W1L[k * D + lane];

    int i0 = (blockIdx.x * 4 + wv) * MM_NPW;
    if (i0 >= N_NODES) return;
    int iEnd = i0 + MM_NPW; if (iEnd > N_NODES) iEnd = N_NODES;

    float xv = X[(size_t)i0 * D + lane];
    for (int i = i0; i < iEnd; ++i) {
        int inext = (i + 1 < N_NODES) ? (i + 1) : i;
        float xnext = X[(size_t)inext * D + lane];

        aSh[wv][lane] = xv;
        asm volatile("s_waitcnt lgkmcnt(0)" ::: "memory");

        float ac0 = 0.f, ac1 = 0.f, ac2 = 0.f, ac3 = 0.f;
#pragma unroll
        for (int c = 0; c < 16; ++c) {
            float4 a4 = *(const float4*)&aSh[wv][c * 4];
            ac0 = fmaf(a4.x, wreg[4 * c + 0], ac0);
            ac1 = fmaf(a4.y, wreg[4 * c + 1], ac1);
            ac2 = fmaf(a4.z, wreg[4 * c + 2], ac2);
            ac3 = fmaf(a4.w, wreg[4 * c + 3], ac3);
        }
        float acc = (ac0 + ac1) + (ac2 + ac3);
        Y16[(size_t)i * D + lane] = (_Float16)(acc * dinv[i]);
        xv = xnext;
    }
}

// ---- fused pull + next-layer matmul: per-lane-feature layout ----
__global__ void __launch_bounds__(256)
k_pullmm(const _Float16* __restrict__ H, const int* __restrict__ esrc,
         const int* __restrict__ base, const float* __restrict__ dinv,
         const float* __restrict__ b_in, const _Float16* __restrict__ Whg,
         _Float16* __restrict__ Hout) {
    __shared__ _Float16 WhL[D * D];   // 8KB swizzled Wt (from k_prepW)
    __shared__ _Float16 aSh[4][D];    // per-wave activation row (128B each)
    {
#pragma unroll
        for (int it = 0; it < 2; ++it) {
            int t = threadIdx.x + it * 256;
            *(half8*)&WhL[t * 8] = *(const half8*)&Whg[t * 8];
        }
    }
    __syncthreads();

    int wv   = threadIdx.x >> 6;
    int lane = threadIdx.x & 63;
    int i    = blockIdx.x * 4 + wv;
    int s0 = base[i], s1 = base[i + 1];

    float a0 = (float)H[(size_t)i * D + lane];   // self contribution
    float a1 = 0.f, a2 = 0.f, a3 = 0.f;

    int p = s0;
    while (p < s1) {
        int cnt = s1 - p;
        if (cnt > 64) cnt = 64;
        int ed = (lane < cnt) ? esrc[p + lane] : 0;
        int j = 0;
        for (; j + 4 <= cnt; j += 4) {
            int e0 = __builtin_amdgcn_readlane(ed, j);
            int e1 = __builtin_amdgcn_readlane(ed, j + 1);
            int e2 = __builtin_amdgcn_readlane(ed, j + 2);
            int e3 = __builtin_amdgcn_readlane(ed, j + 3);
            _Float16 h0 = H[(size_t)e0 * D + lane];
            _Float16 h1 = H[(size_t)e1 * D + lane];
            _Float16 h2 = H[(size_t)e2 * D + lane];
            _Float16 h3 = H[(size_t)e3 * D + lane];
            a0 += (float)h0; a1 += (float)h1; a2 += (float)h2; a3 += (float)h3;
        }
        for (; j < cnt; ++j) {
            int e0 = __builtin_amdgcn_readlane(ed, j);
            a0 += (float)H[(size_t)e0 * D + lane];
        }
        p += cnt;
    }
    float agg = (a0 + a1) + (a2 + a3);

    float di = dinv[i];
    float av = fmaxf(fmaf(agg, di, b_in[lane]), 0.f);
    aSh[wv][lane] = (_Float16)av;
    asm volatile("s_waitcnt lgkmcnt(0)" ::: "memory");

    float part = 0.f;
#pragma unroll
    for (int c = 0; c < 8; ++c) {
        hf8 a8 = *(const hf8*)&aSh[wv][c * 8];                           // broadcast
        hf8 w8 = *(const hf8*)&WhL[lane * 64 + ((c ^ (lane & 7)) * 8)];  // conflict-free
#ifdef USE_DOT2
#pragma unroll
        for (int q = 0; q < 4; ++q) {
            hf2 ap; ap.x = a8[2 * q]; ap.y = a8[2 * q + 1];
            hf2 wp; wp.x = w8[2 * q]; wp.y = w8[2 * q + 1];
            part = __builtin_amdgcn_fdot2(ap, wp, part, false);
        }
#else
#pragma unroll
        for (int t = 0; t < 8; ++t)
            part = fmaf((float)a8[t], (float)w8[t], part);
#endif
    }
    Hout[(size_t)i * D + lane] = (_Float16)(part * di);
}

// ---------------- final pull (layer 3): per-lane-feature, fp16 AGG out ------
__global__ void __launch_bounds__(256)
k_pull(const _Float16* __restrict__ H, const int* __restrict__ esrc,
       const int* __restrict__ base, const float* __restrict__ dinv,
       const float* __restrict__ b, _Float16* __restrict__ AGG16) {
    int wv   = threadIdx.x >> 6;
    int lane = threadIdx.x & 63;
    int i    = blockIdx.x * 4 + wv;
    int s0 = base[i], s1 = base[i + 1];

    float a0 = (float)H[(size_t)i * D + lane];
    float a1 = 0.f, a2 = 0.f, a3 = 0.f;

    int p = s0;
    while (p < s1) {
        int cnt = s1 - p;
        if (cnt > 64) cnt = 64;
        int ed = (lane < cnt) ? esrc[p + lane] : 0;
        int j = 0;
        for (; j + 4 <= cnt; j += 4) {
            int e0 = __builtin_amdgcn_readlane(ed, j);
            int e1 = __builtin_amdgcn_readlane(ed, j + 1);
            int e2 = __builtin_amdgcn_readlane(ed, j + 2);
            int e3 = __builtin_amdgcn_readlane(ed, j + 3);
            _Float16 h0 = H[(size_t)e0 * D + lane];
            _Float16 h1 = H[(size_t)e1 * D + lane];
            _Float16 h2 = H[(size_t)e2 * D + lane];
            _Float16 h3 = H[(size_t)e3 * D + lane];
            a0 += (float)h0; a1 += (float)h1; a2 += (float)h2; a3 += (float)h3;
        }
        for (; j < cnt; ++j) {
            int e0 = __builtin_amdgcn_readlane(ed, j);
            a0 += (float)H[(size_t)e0 * D + lane];
        }
        p += cnt;
    }
    float agg = (a0 + a1) + (a2 + a3);
    float di = dinv[i];
    AGG16[(size_t)i * D + lane] = (_Float16)fmaf(agg, di, b[lane]);
}

// ---- segment-sorted pooling (fp16 in, fp32 accumulate, fused counts) ----
__global__ void __launch_bounds__(256)
k_pool_seg(const _Float16* __restrict__ H16, const int* __restrict__ seg,
           float* __restrict__ pooled, float* __restrict__ counts) {
    int wave = threadIdx.x >> 6;
    int lane = threadIdx.x & 63;
    int n0 = (blockIdx.x * 4 + wave) * 64;
    if (n0 >= N_NODES) return;
    int nEnd = n0 + 64;
    if (nEnd > N_NODES) nEnd = N_NODES;
    int cur = seg[n0];
    float acc = 0.0f;
    int run = 0;
    for (int n = n0; n < nEnd; ++n) {
        int gsg = seg[n];  // wave-uniform
        if (gsg != cur) {
            atomicAdd(&pooled[(size_t)cur * D + lane], acc);
            if (lane == 0) atomicAdd(&counts[cur], (float)run);
            acc = 0.0f; run = 0;
            cur = gsg;
        }
        acc += (float)H16[(size_t)n * D + lane];
        run += 1;
    }
    atomicAdd(&pooled[(size_t)cur * D + lane], acc);
    if (lane == 0) atomicAdd(&counts[cur], (float)run);
}

// ---------------- head ----------------
__global__ void k_out(const float* __restrict__ pooled, const float* __restrict__ counts,
                      const float* __restrict__ Wout, const float* __restrict__ bout,
                      float* __restrict__ out) {
    __shared__ float prow[D];
    int g = blockIdx.x;
    int t = threadIdx.x;
    if (t < D) prow[t] = pooled[(size_t)g * D + t] / fmaxf(counts[g], 1.0f);
    __syncthreads();
    if (t < N_TARGETS) {
        float acc = bout[t];
#pragma unroll
        for (int k = 0; k < D; ++k)
            acc = fmaf(prow[k], Wout[k * N_TARGETS + t], acc);
        out[g * N_TARGETS + t] = acc;
    }
}

// ---------------- driver ----------------

extern "C" void kernel_launch(void* const* d_in, const int* in_sizes, int n_in,
                              void* d_out, int out_size, void* d_ws, size_t ws_size,
                              hipStream_t stream) {
    const float* x    = (const float*)d_in[0];
    const float* W1   = (const float*)d_in[1];
    const float* b1   = (const float*)d_in[2];
    const float* W2   = (const float*)d_in[3];
    const float* b2   = (const float*)d_in[4];
    const float* W3   = (const float*)d_in[5];
    const float* b3   = (const float*)d_in[6];
    const float* Wout = (const float*)d_in[7];
    const float* bout = (const float*)d_in[8];
    const int*   eidx = (const int*)d_in[9];
    const int*   seg  = (const int*)d_in[10];
    const int* src = eidx;
    const int* dst = eidx + N_EDGES;
    float* out = (float*)d_out;

    // workspace layout (~33 MB). staged (19.2 MB) aliases H16A+H16B (dead
    // during CSR build); AGG16 aliases H16B (dead after pullmm#2).
    _Float16* H16A   = (_Float16*)d_ws;                       // 6.4M halfs (12.8MB)
    _Float16* H16B   = H16A + (size_t)N_NODES * D;            // 6.4M halfs
    _Float16* AGG16  = H16B;                                  // alias
    unsigned long long* staged = (unsigned long long*)d_ws;   // alias: 391*6144 pairs
    int*      esrc   = (int*)(H16B + (size_t)N_NODES * D);    // 1.6M
    float*    dinv   = (float*)(esrc + N_EDGES);              // 100k
    int*      base   = (int*)(dinv + N_NODES);                // 100k+1 (+pad)
    float*    pooled = (float*)(base + N_NODES + 4);          // 32768
    float*    counts = pooled + N_GRAPHS * D;                 // 512
    int*      gcur   = (int*)(counts + N_GRAPHS);             // 391 (+pad to 512)
    int*      bstart = gcur + 512;                            // 392 (+pad to 512)
    _Float16* WhA    = (_Float16*)(bstart + 512);             // 4096 halfs (8KB)
    _Float16* WhB    = WhA + 4096;                            // 4096 halfs (8KB)

    const int NB = (N_NODES + 255) / 256;  // 391

    // ---- one-shot fp16 weight prep (transposed + swizzled layout) ----
    k_prepW<<<1, 256, 0, stream>>>(W2, WhA);
    k_prepW<<<1, 256, 0, stream>>>(W3, WhB);

    // ---- CSR build: slab-bucketed scatter with in-bucket degree counting ----
    k_init<<<130, 256, 0, stream>>>(gcur, pooled);
    k_binA<<<(N_EDGES + EPB - 1) / EPB, 256, 0, stream>>>(src, dst, gcur, staged);
    k_scanB<<<1, 512, 0, stream>>>(gcur, bstart);
    k_binB<<<NBUCK, 256, 0, stream>>>(staged, gcur, bstart, esrc, base, dinv);

    // ---- 3 GCN layers (mm1 separate; mm2/mm3 fused into pulls) ----
    const int MMB = (N_NODES + 4 * MM_NPW - 1) / (4 * MM_NPW);  // 1563
    k_mm<<<MMB, 256, 0, stream>>>(x, W1, dinv, H16A);
    k_pullmm<<<N_NODES / 4, 256, 0, stream>>>(H16A, esrc, base, dinv, b1, WhA, H16B);
    k_pullmm<<<N_NODES / 4, 256, 0, stream>>>(H16B, esrc, base, dinv, b2, WhB, H16A);
    k_pull<<<N_NODES / 4, 256, 0, stream>>>(H16A, esrc, base, dinv, b3, AGG16);

    // ---- mean pool (sorted-segment, fused counts) + head ----
    k_pool_seg<<<NB, 256, 0, stream>>>(AGG16, seg, pooled, counts);
    k_out<<<N_GRAPHS, 128, 0, stream>>>(pooled, counts, Wout, bout, out);
}

// Round 9
// 347.108 us; speedup vs baseline: 1.5537x; 1.0288x over previous
//
#include <hip/hip_runtime.h>

#define N_NODES   100000
#define N_EDGES   1600000
#define D         64
#define N_TARGETS 100
#define N_GRAPHS  512
#define NBUCK     391     // ceil(N_NODES / 256): bucket b = dst >> 8
#define EPB       4096    // edges per block in pass A
#define BCAP      6144    // bucket slab capacity (Poisson(4096) + 32 sigma)
#define MM_NPW    16      // nodes per wave in k_mm

typedef _Float16 half4 __attribute__((ext_vector_type(4)));
typedef _Float16 half8 __attribute__((ext_vector_type(8)));
typedef __fp16   hf2   __attribute__((ext_vector_type(2)));   // builtin-compatible
typedef __fp16   hf8   __attribute__((ext_vector_type(8)));

#if defined(__has_builtin)
#if __has_builtin(__builtin_amdgcn_fdot2)
#define USE_DOT2 1
#endif
#endif

// ---- init: zero bucket cursors + pooled/counts ----
__global__ void k_init(int* __restrict__ gcur, float* __restrict__ poolz) {
    int i = blockIdx.x * blockDim.x + threadIdx.x;
    if (i < NBUCK) gcur[i] = 0;
    if (i < N_GRAPHS * D + N_GRAPHS) poolz[i] = 0.0f;
}

// ---- one-shot W -> fp16 transposed + swizzled layout (for k_pullmm) ----
__global__ void k_prepW(const float* __restrict__ W, _Float16* __restrict__ out) {
    int t = threadIdx.x;
#pragma unroll
    for (int it = 0; it < 2; ++it) {
        int idx = t + it * 256;        // 512 (m, c) chunks
        int m = idx >> 3, c = idx & 7;
        half8 hv;
#pragma unroll
        for (int tt = 0; tt < 8; ++tt)
            hv[tt] = (_Float16)W[(8 * c + tt) * 64 + m];
        *(half8*)&out[m * 64 + ((c ^ (m & 7)) * 8)] = hv;
    }
}

// ---- pass A: bucket edges by dst>>8 into fixed-capacity slabs ----
__global__ void __launch_bounds__(256)
k_binA(const int* __restrict__ src, const int* __restrict__ dst,
       int* __restrict__ gcur, unsigned long long* __restrict__ staged) {
    __shared__ int hist[NBUCK];
    __shared__ int boff[NBUCK];
    int tid = threadIdx.x;
    for (int i = tid; i < NBUCK; i += 256) hist[i] = 0;
    __syncthreads();

    int e0 = blockIdx.x * EPB;
    int s_[16], d_[16], r_[16];
#pragma unroll
    for (int k = 0; k < 16; ++k) {
        int e = e0 + k * 256 + tid;
        if (e < N_EDGES) {
            s_[k] = src[e];
            d_[k] = dst[e];
            r_[k] = atomicAdd(&hist[d_[k] >> 8], 1);
        } else {
            d_[k] = -1;
        }
    }
    __syncthreads();
    for (int b = tid; b < NBUCK; b += 256) {
        int h = hist[b];
        boff[b] = (h > 0) ? atomicAdd(&gcur[b], h) : 0;
    }
    __syncthreads();
#pragma unroll
    for (int k = 0; k < 16; ++k) {
        if (d_[k] >= 0) {
            int b = d_[k] >> 8;
            staged[(size_t)b * BCAP + boff[b] + r_[k]] =
                ((unsigned long long)(unsigned)d_[k] << 32) | (unsigned)s_[k];
        }
    }
}

// ---- scan bucket totals -> bucket edge-space starts ----
__global__ void k_scanB(const int* __restrict__ gcur, int* __restrict__ bstart) {
    __shared__ int s[512];
    int t = threadIdx.x;
    int v = (t < NBUCK) ? gcur[t] : 0;
    s[t] = v;
    __syncthreads();
    for (int off = 1; off < 512; off <<= 1) {
        int x = (t >= off) ? s[t - off] : 0;
        __syncthreads();
        s[t] += x;
        __syncthreads();
    }
    if (t < NBUCK) bstart[t] = s[t] - v;
    if (t == 0) bstart[NBUCK] = N_EDGES;
}

// ---- pass B: one block per bucket; LDS degree count + scan + place ----
__global__ void __launch_bounds__(256)
k_binB(const unsigned long long* __restrict__ staged, const int* __restrict__ gcur,
       const int* __restrict__ bstart, int* __restrict__ esrc,
       int* __restrict__ base, float* __restrict__ dinv) {
    __shared__ int s[256];
    __shared__ int lbase[256];
    __shared__ int cur[256];
    int b = blockIdx.x;
    int t = threadIdx.x;
    int n0 = b << 8;
    int Eb = gcur[b];
    int Sb = bstart[b];
    const unsigned long long* sl = staged + (size_t)b * BCAP;

    cur[t] = 0;
    __syncthreads();
    for (int k = t; k < Eb; k += 256) {
        int dl = ((int)(sl[k] >> 32)) & 255;
        atomicAdd(&cur[dl], 1);
    }
    __syncthreads();
    int v = cur[t];
    s[t] = v;
    __syncthreads();
    for (int off = 1; off < 256; off <<= 1) {
        int x = (t >= off) ? s[t - off] : 0;
        __syncthreads();
        s[t] += x;
        __syncthreads();
    }
    lbase[t] = s[t] - v;
    int gi = n0 + t;
    if (gi < N_NODES) {
        base[gi] = Sb + (s[t] - v);
        dinv[gi] = rsqrtf((float)v + 1.0f);   // +1 self-loop
    }
    if (b == 0 && t == 0) base[N_NODES] = N_EDGES;
    cur[t] = 0;
    __syncthreads();
    for (int k = t; k < Eb; k += 256) {
        unsigned long long pd = sl[k];
        int dl = ((int)(pd >> 32)) & 255;
        int pos = Sb + lbase[dl] + atomicAdd(&cur[dl], 1);
        esrc[pos] = (int)(pd & 0xffffffffu);
    }
}

// ------ matmul (layer 1): per-lane-feature, W1 column in registers ----------
__global__ void __launch_bounds__(256)
k_mm(const float* __restrict__ X, const float* __restrict__ W,
     const float* __restrict__ dinv, _Float16* __restrict__ Y16) {
    __shared__ float W1L[D * D];   // 16 KB raw [k][m]
    __shared__ float aSh[4][D];    // per-wave X row
    int tid = threadIdx.x;
#pragma unroll
    for (int it = 0; it < 4; ++it) {
        int idx = (tid + it * 256) * 4;
        *(float4*)&W1L[idx] = *(const float4*)(W + idx);
    }
    __syncthreads();

    int wv = tid >> 6, lane = tid & 63;
    float wreg[D];   // W1[k][lane] for all k
#pragma unroll
    for (int k = 0; k < D; ++k)
        wreg[k] = W1L[k * D + lane];

    int i0 = (blockIdx.x * 4 + wv) * MM_NPW;
    if (i0 >= N_NODES) return;
    int iEnd = i0 + MM_NPW; if (iEnd > N_NODES) iEnd = N_NODES;

    float xv = X[(size_t)i0 * D + lane];
    for (int i = i0; i < iEnd; ++i) {
        int inext = (i + 1 < N_NODES) ? (i + 1) : i;
        float xnext = X[(size_t)inext * D + lane];

        aSh[wv][lane] = xv;
        asm volatile("s_waitcnt lgkmcnt(0)" ::: "memory");

        float ac0 = 0.f, ac1 = 0.f, ac2 = 0.f, ac3 = 0.f;
#pragma unroll
        for (int c = 0; c < 16; ++c) {
            float4 a4 = *(const float4*)&aSh[wv][c * 4];
            ac0 = fmaf(a4.x, wreg[4 * c + 0], ac0);
            ac1 = fmaf(a4.y, wreg[4 * c + 1], ac1);
            ac2 = fmaf(a4.z, wreg[4 * c + 2], ac2);
            ac3 = fmaf(a4.w, wreg[4 * c + 3], ac3);
        }
        float acc = (ac0 + ac1) + (ac2 + ac3);
        Y16[(size_t)i * D + lane] = (_Float16)(acc * dinv[i]);
        xv = xnext;
    }
}

// ---- fused pull + next-layer matmul: 8-lane-group half8 gather (R1-verified
// geometry: g=lane>>3 edge-group, l=lane&7 feature-block, l*8+7 <= 63) +
// per-lane-feature epilogue (R5/R6-verified). 32-edge path = 4 loads in flight.
__global__ void __launch_bounds__(256)
k_pullmm(const _Float16* __restrict__ H, const int* __restrict__ esrc,
         const int* __restrict__ base, const float* __restrict__ dinv,
         const float* __restrict__ b_in, const _Float16* __restrict__ Whg,
         _Float16* __restrict__ Hout) {
    __shared__ _Float16 WhL[D * D];   // 8KB swizzled Wt (from k_prepW)
    __shared__ _Float16 aSh[4][D];    // per-wave activation row
    {
#pragma unroll
        for (int it = 0; it < 2; ++it) {
            int t = threadIdx.x + it * 256;
            *(half8*)&WhL[t * 8] = *(const half8*)&Whg[t * 8];
        }
    }
    __syncthreads();

    int wv   = threadIdx.x >> 6;
    int lane = threadIdx.x & 63;
    int g = lane >> 3, l = lane & 7;
    int i    = blockIdx.x * 4 + wv;
    int s0 = base[i], s1 = base[i + 1];

    float acc[8] = {0.f, 0.f, 0.f, 0.f, 0.f, 0.f, 0.f, 0.f};
    if (g == 0) {           // self contribution (counted once: only group 0)
        half8 sv = *(const half8*)(H + (size_t)i * D + l * 8);
#pragma unroll
        for (int q = 0; q < 8; ++q) acc[q] = (float)sv[q];
    }

    int p = s0;
    while (p < s1) {
        int cnt = s1 - p;
        if (cnt > 64) cnt = 64;
        int ed = (lane < cnt) ? esrc[p + lane] : 0;
        int j = 0;
        for (; j + 32 <= cnt; j += 32) {       // 32 edges: 4 loads in flight
            int e0 = __shfl(ed, j + g, 64);
            int e1 = __shfl(ed, j + 8 + g, 64);
            int e2 = __shfl(ed, j + 16 + g, 64);
            int e3 = __shfl(ed, j + 24 + g, 64);
            half8 v0 = *(const half8*)(H + (size_t)(unsigned)e0 * D + l * 8);
            half8 v1 = *(const half8*)(H + (size_t)(unsigned)e1 * D + l * 8);
            half8 v2 = *(const half8*)(H + (size_t)(unsigned)e2 * D + l * 8);
            half8 v3 = *(const half8*)(H + (size_t)(unsigned)e3 * D + l * 8);
            half8 s01 = v0 + v1;   // v_pk_add_f16 (R3/R4-verified numerics)
            half8 s23 = v2 + v3;
#pragma unroll
            for (int q = 0; q < 8; ++q)
                acc[q] += (float)s01[q] + (float)s23[q];
        }
        for (; j + 8 <= cnt; j += 8) {         // 8 edges: 1 load
            int e0 = __shfl(ed, j + g, 64);
            half8 v0 = *(const half8*)(H + (size_t)(unsigned)e0 * D + l * 8);
#pragma unroll
            for (int q = 0; q < 8; ++q) acc[q] += (float)v0[q];
        }
        if (j < cnt) {                         // tail 1..7 edges
            int idx = j + g;
            int e0 = __shfl(ed, idx & 63, 64);
            if (idx < cnt) {
                half8 v0 = *(const half8*)(H + (size_t)(unsigned)e0 * D + l * 8);
#pragma unroll
                for (int q = 0; q < 8; ++q) acc[q] += (float)v0[q];
            }
        }
        p += cnt;
    }
    // reduce across the 8 edge-groups (same l, different g)
#pragma unroll
    for (int off = 8; off <= 32; off <<= 1) {
#pragma unroll
        for (int q = 0; q < 8; ++q)
            acc[q] += __shfl_xor(acc[q], off, 64);
    }

    float di = dinv[i];
    if (g == 0) {   // 8 lanes write the full 64-feature activation row
        float4 bl0 = *(const float4*)(b_in + l * 8);
        float4 bl1 = *(const float4*)(b_in + l * 8 + 4);
        half8 av;
        av[0] = (_Float16)fmaxf(fmaf(acc[0], di, bl0.x), 0.f);
        av[1] = (_Float16)fmaxf(fmaf(acc[1], di, bl0.y), 0.f);
        av[2] = (_Float16)fmaxf(fmaf(acc[2], di, bl0.z), 0.f);
        av[3] = (_Float16)fmaxf(fmaf(acc[3], di, bl0.w), 0.f);
        av[4] = (_Float16)fmaxf(fmaf(acc[4], di, bl1.x), 0.f);
        av[5] = (_Float16)fmaxf(fmaf(acc[5], di, bl1.y), 0.f);
        av[6] = (_Float16)fmaxf(fmaf(acc[6], di, bl1.z), 0.f);
        av[7] = (_Float16)fmaxf(fmaf(acc[7], di, bl1.w), 0.f);
        *(half8*)&aSh[wv][l * 8] = av;
    }
    asm volatile("s_waitcnt lgkmcnt(0)" ::: "memory");

    float part = 0.f;
#pragma unroll
    for (int c = 0; c < 8; ++c) {
        hf8 a8 = *(const hf8*)&aSh[wv][c * 8];                           // broadcast
        hf8 w8 = *(const hf8*)&WhL[lane * 64 + ((c ^ (lane & 7)) * 8)];  // swizzled
#ifdef USE_DOT2
#pragma unroll
        for (int q = 0; q < 4; ++q) {
            hf2 ap; ap.x = a8[2 * q]; ap.y = a8[2 * q + 1];
            hf2 wp; wp.x = w8[2 * q]; wp.y = w8[2 * q + 1];
            part = __builtin_amdgcn_fdot2(ap, wp, part, false);
        }
#else
#pragma unroll
        for (int t = 0; t < 8; ++t)
            part = fmaf((float)a8[t], (float)w8[t], part);
#endif
    }
    Hout[(size_t)i * D + lane] = (_Float16)(part * di);
}

// ---------------- final pull (layer 3): 8-lane-group gather, fp16 AGG out ---
__global__ void __launch_bounds__(256)
k_pull(const _Float16* __restrict__ H, const int* __restrict__ esrc,
       const int* __restrict__ base, const float* __restrict__ dinv,
       const float* __restrict__ b, _Float16* __restrict__ AGG16) {
    int wv   = threadIdx.x >> 6;
    int lane = threadIdx.x & 63;
    int g = lane >> 3, l = lane & 7;
    int i    = blockIdx.x * 4 + wv;
    int s0 = base[i], s1 = base[i + 1];

    float acc[8] = {0.f, 0.f, 0.f, 0.f, 0.f, 0.f, 0.f, 0.f};
    if (g == 0) {
        half8 sv = *(const half8*)(H + (size_t)i * D + l * 8);
#pragma unroll
        for (int q = 0; q < 8; ++q) acc[q] = (float)sv[q];
    }

    int p = s0;
    while (p < s1) {
        int cnt = s1 - p;
        if (cnt > 64) cnt = 64;
        int ed = (lane < cnt) ? esrc[p + lane] : 0;
        int j = 0;
        for (; j + 32 <= cnt; j += 32) {
            int e0 = __shfl(ed, j + g, 64);
            int e1 = __shfl(ed, j + 8 + g, 64);
            int e2 = __shfl(ed, j + 16 + g, 64);
            int e3 = __shfl(ed, j + 24 + g, 64);
            half8 v0 = *(const half8*)(H + (size_t)(unsigned)e0 * D + l * 8);
            half8 v1 = *(const half8*)(H + (size_t)(unsigned)e1 * D + l * 8);
            half8 v2 = *(const half8*)(H + (size_t)(unsigned)e2 * D + l * 8);
            half8 v3 = *(const half8*)(H + (size_t)(unsigned)e3 * D + l * 8);
            half8 s01 = v0 + v1;
            half8 s23 = v2 + v3;
#pragma unroll
            for (int q = 0; q < 8; ++q)
                acc[q] += (float)s01[q] + (float)s23[q];
        }
        for (; j + 8 <= cnt; j += 8) {
            int e0 = __shfl(ed, j + g, 64);
            half8 v0 = *(const half8*)(H + (size_t)(unsigned)e0 * D + l * 8);
#pragma unroll
            for (int q = 0; q < 8; ++q) acc[q] += (float)v0[q];
        }
        if (j < cnt) {
            int idx = j + g;
            int e0 = __shfl(ed, idx & 63, 64);
            if (idx < cnt) {
                half8 v0 = *(const half8*)(H + (size_t)(unsigned)e0 * D + l * 8);
#pragma unroll
                for (int q = 0; q < 8; ++q) acc[q] += (float)v0[q];
            }
        }
        p += cnt;
    }
#pragma unroll
    for (int off = 8; off <= 32; off <<= 1) {
#pragma unroll
        for (int q = 0; q < 8; ++q)
            acc[q] += __shfl_xor(acc[q], off, 64);
    }

    if (g == 0) {
        float di = dinv[i];
        float4 bl0 = *(const float4*)(b + l * 8);
        float4 bl1 = *(const float4*)(b + l * 8 + 4);
        half8 o;
        o[0] = (_Float16)fmaf(acc[0], di, bl0.x);
        o[1] = (_Float16)fmaf(acc[1], di, bl0.y);
        o[2] = (_Float16)fmaf(acc[2], di, bl0.z);
        o[3] = (_Float16)fmaf(acc[3], di, bl0.w);
        o[4] = (_Float16)fmaf(acc[4], di, bl1.x);
        o[5] = (_Float16)fmaf(acc[5], di, bl1.y);
        o[6] = (_Float16)fmaf(acc[6], di, bl1.z);
        o[7] = (_Float16)fmaf(acc[7], di, bl1.w);
        *(half8*)(AGG16 + (size_t)i * D + l * 8) = o;
    }
}

// ---- segment-sorted pooling (fp16 in, fp32 accumulate, fused counts) ----
__global__ void __launch_bounds__(256)
k_pool_seg(const _Float16* __restrict__ H16, const int* __restrict__ seg,
           float* __restrict__ pooled, float* __restrict__ counts) {
    int wave = threadIdx.x >> 6;
    int lane = threadIdx.x & 63;
    int n0 = (blockIdx.x * 4 + wave) * 64;
    if (n0 >= N_NODES) return;
    int nEnd = n0 + 64;
    if (nEnd > N_NODES) nEnd = N_NODES;
    int cur = seg[n0];
    float acc = 0.0f;
    int run = 0;
    for (int n = n0; n < nEnd; ++n) {
        int gsg = seg[n];  // wave-uniform
        if (gsg != cur) {
            atomicAdd(&pooled[(size_t)cur * D + lane], acc);
            if (lane == 0) atomicAdd(&counts[cur], (float)run);
            acc = 0.0f; run = 0;
            cur = gsg;
        }
        acc += (float)H16[(size_t)n * D + lane];
        run += 1;
    }
    atomicAdd(&pooled[(size_t)cur * D + lane], acc);
    if (lane == 0) atomicAdd(&counts[cur], (float)run);
}

// ---------------- head ----------------
__global__ void k_out(const float* __restrict__ pooled, const float* __restrict__ counts,
                      const float* __restrict__ Wout, const float* __restrict__ bout,
                      float* __restrict__ out) {
    __shared__ float prow[D];
    int g = blockIdx.x;
    int t = threadIdx.x;
    if (t < D) prow[t] = pooled[(size_t)g * D + t] / fmaxf(counts[g], 1.0f);
    __syncthreads();
    if (t < N_TARGETS) {
        float acc = bout[t];
#pragma unroll
        for (int k = 0; k < D; ++k)
            acc = fmaf(prow[k], Wout[k * N_TARGETS + t], acc);
        out[g * N_TARGETS + t] = acc;
    }
}

// ---------------- driver ----------------

extern "C" void kernel_launch(void* const* d_in, const int* in_sizes, int n_in,
                              void* d_out, int out_size, void* d_ws, size_t ws_size,
                              hipStream_t stream) {
    const float* x    = (const float*)d_in[0];
    const float* W1   = (const float*)d_in[1];
    const float* b1   = (const float*)d_in[2];
    const float* W2   = (const float*)d_in[3];
    const float* b2   = (const float*)d_in[4];
    const float* W3   = (const float*)d_in[5];
    const float* b3   = (const float*)d_in[6];
    const float* Wout = (const float*)d_in[7];
    const float* bout = (const float*)d_in[8];
    const int*   eidx = (const int*)d_in[9];
    const int*   seg  = (const int*)d_in[10];
    const int* src = eidx;
    const int* dst = eidx + N_EDGES;
    float* out = (float*)d_out;

    // workspace layout (~33 MB). staged (19.2 MB) aliases H16A+H16B (dead
    // during CSR build); AGG16 aliases H16B (dead after pullmm#2).
    _Float16* H16A   = (_Float16*)d_ws;                       // 6.4M halfs (12.8MB)
    _Float16* H16B   = H16A + (size_t)N_NODES * D;            // 6.4M halfs
    _Float16* AGG16  = H16B;                                  // alias
    unsigned long long* staged = (unsigned long long*)d_ws;   // alias: 391*6144 pairs
    int*      esrc   = (int*)(H16B + (size_t)N_NODES * D);    // 1.6M
    float*    dinv   = (float*)(esrc + N_EDGES);              // 100k
    int*      base   = (int*)(dinv + N_NODES);                // 100k+1 (+pad)
    float*    pooled = (float*)(base + N_NODES + 4);          // 32768
    float*    counts = pooled + N_GRAPHS * D;                 // 512
    int*      gcur   = (int*)(counts + N_GRAPHS);             // 391 (+pad to 512)
    int*      bstart = gcur + 512;                            // 392 (+pad to 512)
    _Float16* WhA    = (_Float16*)(bstart + 512);             // 4096 halfs (8KB)
    _Float16* WhB    = WhA + 4096;                            // 4096 halfs (8KB)

    const int NB = (N_NODES + 255) / 256;  // 391

    // ---- one-shot fp16 weight prep (transposed + swizzled layout) ----
    k_prepW<<<1, 256, 0, stream>>>(W2, WhA);
    k_prepW<<<1, 256, 0, stream>>>(W3, WhB);

    // ---- CSR build: slab-bucketed scatter with in-bucket degree counting ----
    k_init<<<130, 256, 0, stream>>>(gcur, pooled);
    k_binA<<<(N_EDGES + EPB - 1) / EPB, 256, 0, stream>>>(src, dst, gcur, staged);
    k_scanB<<<1, 512, 0, stream>>>(gcur, bstart);
    k_binB<<<NBUCK, 256, 0, stream>>>(staged, gcur, bstart, esrc, base, dinv);

    // ---- 3 GCN layers (mm1 separate; mm2/mm3 fused into pulls) ----
    const int MMB = (N_NODES + 4 * MM_NPW - 1) / (4 * MM_NPW);  // 1563
    k_mm<<<MMB, 256, 0, stream>>>(x, W1, dinv, H16A);
    k_pullmm<<<N_NODES / 4, 256, 0, stream>>>(H16A, esrc, base, dinv, b1, WhA, H16B);
    k_pullmm<<<N_NODES / 4, 256, 0, stream>>>(H16B, esrc, base, dinv, b2, WhB, H16A);
    k_pull<<<N_NODES / 4, 256, 0, stream>>>(H16A, esrc, base, dinv, b3, AGG16);

    // ---- mean pool (sorted-segment, fused counts) + head ----
    k_pool_seg<<<NB, 256, 0, stream>>>(AGG16, seg, pooled, counts);
    k_out<<<N_GRAPHS, 128, 0, stream>>>(pooled, counts, Wout, bout, out);
}

// Round 10
// 320.170 us; speedup vs baseline: 1.6844x; 1.0841x over previous
//
#include <hip/hip_runtime.h>

#define N_NODES   100000
#define N_EDGES   1600000
#define D         64
#define N_TARGETS 100
#define N_GRAPHS  512
#define NBUCK     391     // ceil(N_NODES / 256): bucket b = dst >> 8
#define EPB       4096    // edges per block in pass A
#define BCAP      6144    // bucket slab capacity (Poisson(4096) + 32 sigma)
#define MM_NPW    16      // nodes per wave in k_mm
#define NPN       4       // nodes per wave in pull kernels

typedef _Float16 half4 __attribute__((ext_vector_type(4)));
typedef _Float16 half8 __attribute__((ext_vector_type(8)));
typedef __fp16   hf2   __attribute__((ext_vector_type(2)));   // builtin-compatible
typedef __fp16   hf8   __attribute__((ext_vector_type(8)));

#if defined(__has_builtin)
#if __has_builtin(__builtin_amdgcn_fdot2)
#define USE_DOT2 1
#endif
#endif

// ---- init: zero bucket cursors + pooled/counts ----
__global__ void k_init(int* __restrict__ gcur, float* __restrict__ poolz) {
    int i = blockIdx.x * blockDim.x + threadIdx.x;
    if (i < NBUCK) gcur[i] = 0;
    if (i < N_GRAPHS * D + N_GRAPHS) poolz[i] = 0.0f;
}

// ---- one-shot W -> fp16 transposed + swizzled layout (for k_pullmm) ----
__global__ void k_prepW(const float* __restrict__ W, _Float16* __restrict__ out) {
    int t = threadIdx.x;
#pragma unroll
    for (int it = 0; it < 2; ++it) {
        int idx = t + it * 256;        // 512 (m, c) chunks
        int m = idx >> 3, c = idx & 7;
        half8 hv;
#pragma unroll
        for (int tt = 0; tt < 8; ++tt)
            hv[tt] = (_Float16)W[(8 * c + tt) * 64 + m];
        *(half8*)&out[m * 64 + ((c ^ (m & 7)) * 8)] = hv;
    }
}

// ---- pass A: bucket edges by dst>>8 into fixed-capacity slabs ----
__global__ void __launch_bounds__(256)
k_binA(const int* __restrict__ src, const int* __restrict__ dst,
       int* __restrict__ gcur, unsigned long long* __restrict__ staged) {
    __shared__ int hist[NBUCK];
    __shared__ int boff[NBUCK];
    int tid = threadIdx.x;
    for (int i = tid; i < NBUCK; i += 256) hist[i] = 0;
    __syncthreads();

    int e0 = blockIdx.x * EPB;
    int s_[16], d_[16], r_[16];
#pragma unroll
    for (int k = 0; k < 16; ++k) {
        int e = e0 + k * 256 + tid;
        if (e < N_EDGES) {
            s_[k] = src[e];
            d_[k] = dst[e];
            r_[k] = atomicAdd(&hist[d_[k] >> 8], 1);
        } else {
            d_[k] = -1;
        }
    }
    __syncthreads();
    for (int b = tid; b < NBUCK; b += 256) {
        int h = hist[b];
        boff[b] = (h > 0) ? atomicAdd(&gcur[b], h) : 0;
    }
    __syncthreads();
#pragma unroll
    for (int k = 0; k < 16; ++k) {
        if (d_[k] >= 0) {
            int b = d_[k] >> 8;
            staged[(size_t)b * BCAP + boff[b] + r_[k]] =
                ((unsigned long long)(unsigned)d_[k] << 32) | (unsigned)s_[k];
        }
    }
}

// ---- scan bucket totals -> bucket edge-space starts ----
__global__ void k_scanB(const int* __restrict__ gcur, int* __restrict__ bstart) {
    __shared__ int s[512];
    int t = threadIdx.x;
    int v = (t < NBUCK) ? gcur[t] : 0;
    s[t] = v;
    __syncthreads();
    for (int off = 1; off < 512; off <<= 1) {
        int x = (t >= off) ? s[t - off] : 0;
        __syncthreads();
        s[t] += x;
        __syncthreads();
    }
    if (t < NBUCK) bstart[t] = s[t] - v;
    if (t == 0) bstart[NBUCK] = N_EDGES;
}

// ---- pass B: one block per bucket; LDS degree count + scan + place ----
__global__ void __launch_bounds__(256)
k_binB(const unsigned long long* __restrict__ staged, const int* __restrict__ gcur,
       const int* __restrict__ bstart, int* __restrict__ esrc,
       int* __restrict__ base, float* __restrict__ dinv) {
    __shared__ int s[256];
    __shared__ int lbase[256];
    __shared__ int cur[256];
    int b = blockIdx.x;
    int t = threadIdx.x;
    int n0 = b << 8;
    int Eb = gcur[b];
    int Sb = bstart[b];
    const unsigned long long* sl = staged + (size_t)b * BCAP;

    cur[t] = 0;
    __syncthreads();
    for (int k = t; k < Eb; k += 256) {
        int dl = ((int)(sl[k] >> 32)) & 255;
        atomicAdd(&cur[dl], 1);
    }
    __syncthreads();
    int v = cur[t];
    s[t] = v;
    __syncthreads();
    for (int off = 1; off < 256; off <<= 1) {
        int x = (t >= off) ? s[t - off] : 0;
        __syncthreads();
        s[t] += x;
        __syncthreads();
    }
    lbase[t] = s[t] - v;
    int gi = n0 + t;
    if (gi < N_NODES) {
        base[gi] = Sb + (s[t] - v);
        dinv[gi] = rsqrtf((float)v + 1.0f);   // +1 self-loop
    }
    if (b == 0 && t == 0) base[N_NODES] = N_EDGES;
    cur[t] = 0;
    __syncthreads();
    for (int k = t; k < Eb; k += 256) {
        unsigned long long pd = sl[k];
        int dl = ((int)(pd >> 32)) & 255;
        int pos = Sb + lbase[dl] + atomicAdd(&cur[dl], 1);
        esrc[pos] = (int)(pd & 0xffffffffu);
    }
}

// ------ matmul (layer 1): per-lane-feature, W1 column in registers ----------
__global__ void __launch_bounds__(256)
k_mm(const float* __restrict__ X, const float* __restrict__ W,
     const float* __restrict__ dinv, _Float16* __restrict__ Y16) {
    __shared__ float W1L[D * D];   // 16 KB raw [k][m]
    __shared__ float aSh[4][D];    // per-wave X row
    int tid = threadIdx.x;
#pragma unroll
    for (int it = 0; it < 4; ++it) {
        int idx = (tid + it * 256) * 4;
        *(float4*)&W1L[idx] = *(const float4*)(W + idx);
    }
    __syncthreads();

    int wv = tid >> 6, lane = tid & 63;
    float wreg[D];   // W1[k][lane] for all k
#pragma unroll
    for (int k = 0; k < D; ++k)
        wreg[k] = W1L[k * D + lane];

    int i0 = (blockIdx.x * 4 + wv) * MM_NPW;
    if (i0 >= N_NODES) return;
    int iEnd = i0 + MM_NPW; if (iEnd > N_NODES) iEnd = N_NODES;

    float xv = X[(size_t)i0 * D + lane];
    for (int i = i0; i < iEnd; ++i) {
        int inext = (i + 1 < N_NODES) ? (i + 1) : i;
        float xnext = X[(size_t)inext * D + lane];

        aSh[wv][lane] = xv;
        asm volatile("s_waitcnt lgkmcnt(0)" ::: "memory");

        float ac0 = 0.f, ac1 = 0.f, ac2 = 0.f, ac3 = 0.f;
#pragma unroll
        for (int c = 0; c < 16; ++c) {
            float4 a4 = *(const float4*)&aSh[wv][c * 4];
            ac0 = fmaf(a4.x, wreg[4 * c + 0], ac0);
            ac1 = fmaf(a4.y, wreg[4 * c + 1], ac1);
            ac2 = fmaf(a4.z, wreg[4 * c + 2], ac2);
            ac3 = fmaf(a4.w, wreg[4 * c + 3], ac3);
        }
        float acc = (ac0 + ac1) + (ac2 + ac3);
        Y16[(size_t)i * D + lane] = (_Float16)(acc * dinv[i]);
        xv = xnext;
    }
}

// ---- fused pull + matmul: R8 gather + LDS transpose-reduce + dot2 epilogue,
// NPN=4 nodes/wave (prologue+WhL staging amortized). Reduce: each lane writes
// 8 partials to red[wv][g][.], lane f then sums the 8 group-partials of
// feature f (2-way bank reads = free; +4 pad spreads the transpose writes).
__global__ void __launch_bounds__(256)
k_pullmm(const _Float16* __restrict__ H, const int* __restrict__ esrc,
         const int* __restrict__ base, const float* __restrict__ dinv,
         const float* __restrict__ b_in, const _Float16* __restrict__ Whg,
         _Float16* __restrict__ Hout) {
    __shared__ _Float16 WhL[D * D];        // 8KB swizzled Wt
    __shared__ float    red[4][8][D + 4];  // 8.5KB transpose-reduce tile
    __shared__ _Float16 aSh[4][D];         // 512B activation rows
    {
#pragma unroll
        for (int it = 0; it < 2; ++it) {
            int t = threadIdx.x + it * 256;
            *(half8*)&WhL[t * 8] = *(const half8*)&Whg[t * 8];
        }
    }
    __syncthreads();

    int wv   = threadIdx.x >> 6;
    int lane = threadIdx.x & 63;
    int g = lane >> 3, l = lane & 7;
    float bias = b_in[lane];
    int i0 = (blockIdx.x * 4 + wv) * NPN;

    for (int n = 0; n < NPN; ++n) {
        int i = i0 + n;
        int s0 = base[i], s1 = base[i + 1];

        float acc[8] = {0.f, 0.f, 0.f, 0.f, 0.f, 0.f, 0.f, 0.f};
        if (g == 0) {       // self contribution (group 0 only)
            half8 sv = *(const half8*)(H + (size_t)i * D + l * 8);
#pragma unroll
            for (int q = 0; q < 8; ++q) acc[q] = (float)sv[q];
        }

        int p = s0;
        while (p < s1) {
            int cnt = s1 - p;
            if (cnt > 64) cnt = 64;
            int ed = (lane < cnt) ? esrc[p + lane] : 0;
            int j = 0;
            for (; j + 32 <= cnt; j += 32) {
                int e0 = __shfl(ed, j + g, 64);
                int e1 = __shfl(ed, j + 8 + g, 64);
                int e2 = __shfl(ed, j + 16 + g, 64);
                int e3 = __shfl(ed, j + 24 + g, 64);
                half8 v0 = *(const half8*)(H + (size_t)(unsigned)e0 * D + l * 8);
                half8 v1 = *(const half8*)(H + (size_t)(unsigned)e1 * D + l * 8);
                half8 v2 = *(const half8*)(H + (size_t)(unsigned)e2 * D + l * 8);
                half8 v3 = *(const half8*)(H + (size_t)(unsigned)e3 * D + l * 8);
                half8 s01 = v0 + v1;
                half8 s23 = v2 + v3;
#pragma unroll
                for (int q = 0; q < 8; ++q)
                    acc[q] += (float)s01[q] + (float)s23[q];
            }
            for (; j + 16 <= cnt; j += 16) {
                int e0 = __shfl(ed, j + g, 64);
                int e1 = __shfl(ed, j + 8 + g, 64);
                half8 v0 = *(const half8*)(H + (size_t)(unsigned)e0 * D + l * 8);
                half8 v1 = *(const half8*)(H + (size_t)(unsigned)e1 * D + l * 8);
                half8 s01 = v0 + v1;
#pragma unroll
                for (int q = 0; q < 8; ++q) acc[q] += (float)s01[q];
            }
            for (; j + 8 <= cnt; j += 8) {
                int e0 = __shfl(ed, j + g, 64);
                half8 v0 = *(const half8*)(H + (size_t)(unsigned)e0 * D + l * 8);
#pragma unroll
                for (int q = 0; q < 8; ++q) acc[q] += (float)v0[q];
            }
            if (j < cnt) {
                int idx = j + g;
                int e0 = __shfl(ed, idx & 63, 64);
                if (idx < cnt) {
                    half8 v0 = *(const half8*)(H + (size_t)(unsigned)e0 * D + l * 8);
#pragma unroll
                    for (int q = 0; q < 8; ++q) acc[q] += (float)v0[q];
                }
            }
            p += cnt;
        }

        // ---- LDS transpose-reduce (replaces 24-bpermute shfl tree) ----
        *(float4*)&red[wv][g][l * 8]     = make_float4(acc[0], acc[1], acc[2], acc[3]);
        *(float4*)&red[wv][g][l * 8 + 4] = make_float4(acc[4], acc[5], acc[6], acc[7]);
        asm volatile("s_waitcnt lgkmcnt(0)" ::: "memory");
        float agg = 0.f;
#pragma unroll
        for (int gg = 0; gg < 8; ++gg)
            agg += red[wv][gg][lane];

        float di = dinv[i];
        float av = fmaxf(fmaf(agg, di, bias), 0.f);
        aSh[wv][lane] = (_Float16)av;
        asm volatile("s_waitcnt lgkmcnt(0)" ::: "memory");

        float part = 0.f;
#pragma unroll
        for (int c = 0; c < 8; ++c) {
            hf8 a8 = *(const hf8*)&aSh[wv][c * 8];                           // broadcast
            hf8 w8 = *(const hf8*)&WhL[lane * 64 + ((c ^ (lane & 7)) * 8)];  // swizzled
#ifdef USE_DOT2
#pragma unroll
            for (int q = 0; q < 4; ++q) {
                hf2 ap; ap.x = a8[2 * q]; ap.y = a8[2 * q + 1];
                hf2 wp; wp.x = w8[2 * q]; wp.y = w8[2 * q + 1];
                part = __builtin_amdgcn_fdot2(ap, wp, part, false);
            }
#else
#pragma unroll
            for (int t = 0; t < 8; ++t)
                part = fmaf((float)a8[t], (float)w8[t], part);
#endif
        }
        Hout[(size_t)i * D + lane] = (_Float16)(part * di);
    }
}

// ---------------- final pull (layer 3): gather + transpose-reduce ----------
__global__ void __launch_bounds__(256)
k_pull(const _Float16* __restrict__ H, const int* __restrict__ esrc,
       const int* __restrict__ base, const float* __restrict__ dinv,
       const float* __restrict__ b, _Float16* __restrict__ AGG16) {
    __shared__ float red[4][8][D + 4];
    int wv   = threadIdx.x >> 6;
    int lane = threadIdx.x & 63;
    int g = lane >> 3, l = lane & 7;
    float bias = b[lane];
    int i0 = (blockIdx.x * 4 + wv) * NPN;

    for (int n = 0; n < NPN; ++n) {
        int i = i0 + n;
        int s0 = base[i], s1 = base[i + 1];

        float acc[8] = {0.f, 0.f, 0.f, 0.f, 0.f, 0.f, 0.f, 0.f};
        if (g == 0) {
            half8 sv = *(const half8*)(H + (size_t)i * D + l * 8);
#pragma unroll
            for (int q = 0; q < 8; ++q) acc[q] = (float)sv[q];
        }

        int p = s0;
        while (p < s1) {
            int cnt = s1 - p;
            if (cnt > 64) cnt = 64;
            int ed = (lane < cnt) ? esrc[p + lane] : 0;
            int j = 0;
            for (; j + 32 <= cnt; j += 32) {
                int e0 = __shfl(ed, j + g, 64);
                int e1 = __shfl(ed, j + 8 + g, 64);
                int e2 = __shfl(ed, j + 16 + g, 64);
                int e3 = __shfl(ed, j + 24 + g, 64);
                half8 v0 = *(const half8*)(H + (size_t)(unsigned)e0 * D + l * 8);
                half8 v1 = *(const half8*)(H + (size_t)(unsigned)e1 * D + l * 8);
                half8 v2 = *(const half8*)(H + (size_t)(unsigned)e2 * D + l * 8);
                half8 v3 = *(const half8*)(H + (size_t)(unsigned)e3 * D + l * 8);
                half8 s01 = v0 + v1;
                half8 s23 = v2 + v3;
#pragma unroll
                for (int q = 0; q < 8; ++q)
                    acc[q] += (float)s01[q] + (float)s23[q];
            }
            for (; j + 16 <= cnt; j += 16) {
                int e0 = __shfl(ed, j + g, 64);
                int e1 = __shfl(ed, j + 8 + g, 64);
                half8 v0 = *(const half8*)(H + (size_t)(unsigned)e0 * D + l * 8);
                half8 v1 = *(const half8*)(H + (size_t)(unsigned)e1 * D + l * 8);
                half8 s01 = v0 + v1;
#pragma unroll
                for (int q = 0; q < 8; ++q) acc[q] += (float)s01[q];
            }
            for (; j + 8 <= cnt; j += 8) {
                int e0 = __shfl(ed, j + g, 64);
                half8 v0 = *(const half8*)(H + (size_t)(unsigned)e0 * D + l * 8);
#pragma unroll
                for (int q = 0; q < 8; ++q) acc[q] += (float)v0[q];
            }
            if (j < cnt) {
                int idx = j + g;
                int e0 = __shfl(ed, idx & 63, 64);
                if (idx < cnt) {
                    half8 v0 = *(const half8*)(H + (size_t)(unsigned)e0 * D + l * 8);
#pragma unroll
                    for (int q = 0; q < 8; ++q) acc[q] += (float)v0[q];
                }
            }
            p += cnt;
        }

        *(float4*)&red[wv][g][l * 8]     = make_float4(acc[0], acc[1], acc[2], acc[3]);
        *(float4*)&red[wv][g][l * 8 + 4] = make_float4(acc[4], acc[5], acc[6], acc[7]);
        asm volatile("s_waitcnt lgkmcnt(0)" ::: "memory");
        float agg = 0.f;
#pragma unroll
        for (int gg = 0; gg < 8; ++gg)
            agg += red[wv][gg][lane];
        asm volatile("s_waitcnt lgkmcnt(0)" ::: "memory");

        AGG16[(size_t)i * D + lane] = (_Float16)fmaf(agg, dinv[i], bias);
    }
}

// ---- segment-sorted pooling (fp16 in, fp32 accumulate, fused counts) ----
__global__ void __launch_bounds__(256)
k_pool_seg(const _Float16* __restrict__ H16, const int* __restrict__ seg,
           float* __restrict__ pooled, float* __restrict__ counts) {
    int wave = threadIdx.x >> 6;
    int lane = threadIdx.x & 63;
    int n0 = (blockIdx.x * 4 + wave) * 64;
    if (n0 >= N_NODES) return;
    int nEnd = n0 + 64;
    if (nEnd > N_NODES) nEnd = N_NODES;
    int cur = seg[n0];
    float acc = 0.0f;
    int run = 0;
    for (int n = n0; n < nEnd; ++n) {
        int gsg = seg[n];  // wave-uniform
        if (gsg != cur) {
            atomicAdd(&pooled[(size_t)cur * D + lane], acc);
            if (lane == 0) atomicAdd(&counts[cur], (float)run);
            acc = 0.0f; run = 0;
            cur = gsg;
        }
        acc += (float)H16[(size_t)n * D + lane];
        run += 1;
    }
    atomicAdd(&pooled[(size_t)cur * D + lane], acc);
    if (lane == 0) atomicAdd(&counts[cur], (float)run);
}

// ---------------- head ----------------
__global__ void k_out(const float* __restrict__ pooled, const float* __restrict__ counts,
                      const float* __restrict__ Wout, const float* __restrict__ bout,
                      float* __restrict__ out) {
    __shared__ float prow[D];
    int g = blockIdx.x;
    int t = threadIdx.x;
    if (t < D) prow[t] = pooled[(size_t)g * D + t] / fmaxf(counts[g], 1.0f);
    __syncthreads();
    if (t < N_TARGETS) {
        float acc = bout[t];
#pragma unroll
        for (int k = 0; k < D; ++k)
            acc = fmaf(prow[k], Wout[k * N_TARGETS + t], acc);
        out[g * N_TARGETS + t] = acc;
    }
}

// ---------------- driver ----------------

extern "C" void kernel_launch(void* const* d_in, const int* in_sizes, int n_in,
                              void* d_out, int out_size, void* d_ws, size_t ws_size,
                              hipStream_t stream) {
    const float* x    = (const float*)d_in[0];
    const float* W1   = (const float*)d_in[1];
    const float* b1   = (const float*)d_in[2];
    const float* W2   = (const float*)d_in[3];
    const float* b2   = (const float*)d_in[4];
    const float* W3   = (const float*)d_in[5];
    const float* b3   = (const float*)d_in[6];
    const float* Wout = (const float*)d_in[7];
    const float* bout = (const float*)d_in[8];
    const int*   eidx = (const int*)d_in[9];
    const int*   seg  = (const int*)d_in[10];
    const int* src = eidx;
    const int* dst = eidx + N_EDGES;
    float* out = (float*)d_out;

    // workspace layout (~33 MB). staged (19.2 MB) aliases H16A+H16B (dead
    // during CSR build); AGG16 aliases H16B (dead after pullmm#2).
    _Float16* H16A   = (_Float16*)d_ws;                       // 6.4M halfs (12.8MB)
    _Float16* H16B   = H16A + (size_t)N_NODES * D;            // 6.4M halfs
    _Float16* AGG16  = H16B;                                  // alias
    unsigned long long* staged = (unsigned long long*)d_ws;   // alias: 391*6144 pairs
    int*      esrc   = (int*)(H16B + (size_t)N_NODES * D);    // 1.6M
    float*    dinv   = (float*)(esrc + N_EDGES);              // 100k
    int*      base   = (int*)(dinv + N_NODES);                // 100k+1 (+pad)
    float*    pooled = (float*)(base + N_NODES + 4);          // 32768
    float*    counts = pooled + N_GRAPHS * D;                 // 512
    int*      gcur   = (int*)(counts + N_GRAPHS);             // 391 (+pad to 512)
    int*      bstart = gcur + 512;                            // 392 (+pad to 512)
    _Float16* WhA    = (_Float16*)(bstart + 512);             // 4096 halfs (8KB)
    _Float16* WhB    = WhA + 4096;                            // 4096 halfs (8KB)

    const int NB = (N_NODES + 255) / 256;  // 391

    // ---- one-shot fp16 weight prep (transposed + swizzled layout) ----
    k_prepW<<<1, 256, 0, stream>>>(W2, WhA);
    k_prepW<<<1, 256, 0, stream>>>(W3, WhB);

    // ---- CSR build: slab-bucketed scatter with in-bucket degree counting ----
    k_init<<<130, 256, 0, stream>>>(gcur, pooled);
    k_binA<<<(N_EDGES + EPB - 1) / EPB, 256, 0, stream>>>(src, dst, gcur, staged);
    k_scanB<<<1, 512, 0, stream>>>(gcur, bstart);
    k_binB<<<NBUCK, 256, 0, stream>>>(staged, gcur, bstart, esrc, base, dinv);

    // ---- 3 GCN layers (mm1 separate; mm2/mm3 fused into pulls) ----
    const int MMB = (N_NODES + 4 * MM_NPW - 1) / (4 * MM_NPW);  // 1563
    const int PB  = N_NODES / (4 * NPN);                        // 6250
    k_mm<<<MMB, 256, 0, stream>>>(x, W1, dinv, H16A);
    k_pullmm<<<PB, 256, 0, stream>>>(H16A, esrc, base, dinv, b1, WhA, H16B);
    k_pullmm<<<PB, 256, 0, stream>>>(H16B, esrc, base, dinv, b2, WhB, H16A);
    k_pull<<<PB, 256, 0, stream>>>(H16A, esrc, base, dinv, b3, AGG16);

    // ---- mean pool (sorted-segment, fused counts) + head ----
    k_pool_seg<<<NB, 256, 0, stream>>>(AGG16, seg, pooled, counts);
    k_out<<<N_GRAPHS, 128, 0, stream>>>(pooled, counts, Wout, bout, out);
}